// Round 5
// baseline (4815.181 us; speedup 1.0000x reference)
//
#include <hip/hip_runtime.h>
#include <stdint.h>

typedef unsigned int u32;
typedef unsigned long long u64;
typedef unsigned short ushort;
typedef __attribute__((ext_vector_type(8))) short bf16x8;
typedef __attribute__((ext_vector_type(4))) float f32x4;

#define JAX_PARTITIONABLE 1

#define HD     1024
#define BBATCH 64
#define TSTEP  32
#define VOCAB  32000
#define NROWS  2048      // TSTEP * BBATCH
#define GATE6  6144      // 6 * HD
#define NCB    250       // 32000 / 128 col-blocks
#define NCAND  16
#define GRU_BLOCKS 384   // 192 col-tiles x 2 K-split (matches R4 numerics)

// ---------------- Threefry-2x32 (matches jax._src.prng) ----------------
__device__ __forceinline__ void threefry2x32(u32 k0, u32 k1, u32 x0, u32 x1,
                                             u32& y0, u32& y1) {
  u32 ks2 = k0 ^ k1 ^ 0x1BD11BDAu;
  x0 += k0; x1 += k1;
#define TFR(r) do { x0 += x1; x1 = (x1 << (r)) | (x1 >> (32 - (r))); x1 ^= x0; } while (0)
  TFR(13); TFR(15); TFR(26); TFR(6);   x0 += k1;  x1 += ks2 + 1u;
  TFR(17); TFR(29); TFR(16); TFR(24);  x0 += ks2; x1 += k0 + 2u;
  TFR(13); TFR(15); TFR(26); TFR(6);   x0 += k0;  x1 += k1 + 3u;
  TFR(17); TFR(29); TFR(16); TFR(24);  x0 += k1;  x1 += ks2 + 4u;
  TFR(13); TFR(15); TFR(26); TFR(6);   x0 += ks2; x1 += k0 + 5u;
#undef TFR
  y0 = x0; y1 = x1;
}

__device__ __forceinline__ u32 jax_random_bits(u32 n) {
#if JAX_PARTITIONABLE
  u32 y0, y1; threefry2x32(0u, 42u, 0u, n, y0, y1);
  return y0 ^ y1;
#else
  u32 y0, y1;
  if (n < 8192u) { threefry2x32(0u, 42u, n, n + 8192u, y0, y1); return y0; }
  else           { threefry2x32(0u, 42u, n - 8192u, n, y0, y1); return y1; }
#endif
}

// value-desc, tie -> lower vocab index wins
__device__ __forceinline__ u64 packkey(float v, int idx) {
  u32 b = __float_as_uint(v);
  b = (b & 0x80000000u) ? ~b : (b | 0x80000000u);
  return ((u64)b << 32) | (u64)(~(u32)idx);
}

__device__ __forceinline__ void insert4(u64* t4, u64 k) {
  if (k > t4[3]) {
    t4[3] = k;
    if (t4[3] > t4[2]) { u64 tm = t4[2]; t4[2] = t4[3]; t4[3] = tm; }
    if (t4[2] > t4[1]) { u64 tm = t4[1]; t4[1] = t4[2]; t4[2] = tm; }
    if (t4[1] > t4[0]) { u64 tm = t4[0]; t4[0] = t4[1]; t4[1] = tm; }
  }
}

__device__ __forceinline__ ushort f2bf_rne(float x) {
  u32 u = __float_as_uint(x);
  return (ushort)((u + 0x7fffu + ((u >> 16) & 1u)) >> 16);
}
__device__ __forceinline__ float bf2f(ushort h) {
  return __uint_as_float(((u32)h) << 16);
}

typedef const __attribute__((address_space(1))) void* gas_ptr;
typedef __attribute__((address_space(3))) void* las_ptr;
__device__ __forceinline__ void gload16(const void* g, void* l) {
  __builtin_amdgcn_global_load_lds((gas_ptr)g, (las_ptr)l, 16, 0, 0);
}

// ---------------- two-level grid barrier (8 groups by bid&7) ----------------
// layout (u32 idx): grp cnt g*32, grp gen 256+g*32, glob cnt 512, glob gen 544
__device__ __forceinline__ void grid_bar2(u32* B, int nPerGrp) {
  __syncthreads();
  if (threadIdx.x == 0) {
    __threadfence();
    const int g = blockIdx.x & 7;
    u32* gc = B + g * 32;
    u32* gg = B + 256 + g * 32;
    u32 mygen = __hip_atomic_load(gg, __ATOMIC_RELAXED, __HIP_MEMORY_SCOPE_AGENT);
    u32 a = __hip_atomic_fetch_add(gc, 1u, __ATOMIC_ACQ_REL, __HIP_MEMORY_SCOPE_AGENT);
    if (a == (u32)nPerGrp - 1) {
      __hip_atomic_store(gc, 0u, __ATOMIC_RELAXED, __HIP_MEMORY_SCOPE_AGENT);
      u32* GC = B + 512; u32* GG = B + 544;
      u32 mg = __hip_atomic_load(GG, __ATOMIC_RELAXED, __HIP_MEMORY_SCOPE_AGENT);
      u32 ga = __hip_atomic_fetch_add(GC, 1u, __ATOMIC_ACQ_REL, __HIP_MEMORY_SCOPE_AGENT);
      if (ga == 7u) {
        __hip_atomic_store(GC, 0u, __ATOMIC_RELAXED, __HIP_MEMORY_SCOPE_AGENT);
        __hip_atomic_fetch_add(GG, 1u, __ATOMIC_RELEASE, __HIP_MEMORY_SCOPE_AGENT);
      } else {
        while (__hip_atomic_load(GG, __ATOMIC_ACQUIRE, __HIP_MEMORY_SCOPE_AGENT) == mg)
          __builtin_amdgcn_s_sleep(1);
      }
      __hip_atomic_fetch_add(gg, 1u, __ATOMIC_RELEASE, __HIP_MEMORY_SCOPE_AGENT);
    } else {
      while (__hip_atomic_load(gg, __ATOMIC_ACQUIRE, __HIP_MEMORY_SCOPE_AGENT) == mygen)
        __builtin_amdgcn_s_sleep(1);
    }
  }
  __syncthreads();
}

// ---------------- fp32 -> bf16 bulk convert ----------------
__global__ __launch_bounds__(256) void tobf16(const float* __restrict__ src,
                                              ushort* __restrict__ dst, int n8) {
  int i = blockIdx.x * 256 + threadIdx.x;
  const int stride = gridDim.x * 256;
  for (; i < n8; i += stride) {
    const float4* s4 = (const float4*)src + (size_t)i * 2;
    float4 a = s4[0], b = s4[1];
    u32 o0 = f2bf_rne(a.x) | ((u32)f2bf_rne(a.y) << 16);
    u32 o1 = f2bf_rne(a.z) | ((u32)f2bf_rne(a.w) << 16);
    u32 o2 = f2bf_rne(b.x) | ((u32)f2bf_rne(b.y) << 16);
    u32 o3 = f2bf_rne(b.z) | ((u32)f2bf_rne(b.w) << 16);
    ((uint4*)dst)[i] = make_uint4(o0, o1, o2, o3);
  }
}

// ---------------- W_ih|W_hh -> concat bf16 3-level split ----------------
__global__ __launch_bounds__(256) void tobf16x3_gru(
    const float* __restrict__ Wih, const float* __restrict__ Whh,
    ushort* __restrict__ w1, ushort* __restrict__ w2, ushort* __restrict__ w3,
    int n8) {
  int i = blockIdx.x * 256 + threadIdx.x;
  const int stride = gridDim.x * 256;
  const int half = 3072 * HD / 8;
  for (; i < n8; i += stride) {
    const float4* s4 = (i < half) ? ((const float4*)Wih + (size_t)i * 2)
                                  : ((const float4*)Whh + (size_t)(i - half) * 2);
    float v[8];
    float4 a = s4[0], b = s4[1];
    v[0]=a.x; v[1]=a.y; v[2]=a.z; v[3]=a.w; v[4]=b.x; v[5]=b.y; v[6]=b.z; v[7]=b.w;
    ushort p1[8], p2[8], p3[8];
#pragma unroll
    for (int e = 0; e < 8; ++e) {
      p1[e] = f2bf_rne(v[e]);
      float r1 = v[e] - bf2f(p1[e]);
      p2[e] = f2bf_rne(r1);
      float r2 = r1 - bf2f(p2[e]);
      p3[e] = f2bf_rne(r2);
    }
    u32 o1[4], o2[4], o3[4];
#pragma unroll
    for (int e = 0; e < 4; ++e) {
      o1[e] = p1[2*e] | ((u32)p1[2*e+1] << 16);
      o2[e] = p2[2*e] | ((u32)p2[2*e+1] << 16);
      o3[e] = p3[2*e] | ((u32)p3[2*e+1] << 16);
    }
    ((uint4*)w1)[i] = make_uint4(o1[0], o1[1], o1[2], o1[3]);
    ((uint4*)w2)[i] = make_uint4(o2[0], o2[1], o2[2], o2[3]);
    ((uint4*)w3)[i] = make_uint4(o3[0], o3[1], o3[2], o3[3]);
  }
}

// ---------------- fc_in skinny NT GEMM (fp32, one-time) ----------------
__global__ __launch_bounds__(256) void gemm64_nt(
    const float* __restrict__ A, const float* __restrict__ B,
    float* __restrict__ part) {
  __shared__ float4 As4[64 * 33];
  __shared__ float4 Bs4[32 * 33];
  const int tid = threadIdx.x;
  const int n0 = blockIdx.x * 32;
  const float* Brow = B + (size_t)n0 * HD;
  const int ks = blockIdx.y * 256;
  const int tc = tid & 7, trg = tid >> 3;
  float acc[2][4] = {};
  for (int kc = 0; kc < 2; ++kc) {
    const int k0 = ks + kc * 128;
#pragma unroll
    for (int l = 0; l < 8; ++l) {
      int m = tid + l * 256; int row = m >> 5, k4 = m & 31;
      As4[row * 33 + k4] = *(const float4*)(A + (size_t)row * HD + k0 + k4 * 4);
    }
#pragma unroll
    for (int l = 0; l < 4; ++l) {
      int m = tid + l * 256; int row = m >> 5, k4 = m & 31;
      Bs4[row * 33 + k4] = *(const float4*)(Brow + (size_t)row * HD + k0 + k4 * 4);
    }
    __syncthreads();
#pragma unroll
    for (int kq = 0; kq < 32; ++kq) {
      float4 av[2], bv[4];
      av[0] = As4[trg * 33 + kq];
      av[1] = As4[(trg + 32) * 33 + kq];
      bv[0] = Bs4[tc * 33 + kq];
      bv[1] = Bs4[(tc + 8) * 33 + kq];
      bv[2] = Bs4[(tc + 16) * 33 + kq];
      bv[3] = Bs4[(tc + 24) * 33 + kq];
#pragma unroll
      for (int i = 0; i < 2; ++i)
#pragma unroll
        for (int j = 0; j < 4; ++j) {
          acc[i][j] += av[i].x * bv[j].x;
          acc[i][j] += av[i].y * bv[j].y;
          acc[i][j] += av[i].z * bv[j].z;
          acc[i][j] += av[i].w * bv[j].w;
        }
    }
    __syncthreads();
  }
  float* P = part + (size_t)blockIdx.y * BBATCH * HD;
#pragma unroll
  for (int i = 0; i < 2; ++i) {
    int b = trg + 32 * i;
#pragma unroll
    for (int j = 0; j < 4; ++j)
      P[(size_t)b * HD + n0 + tc + 8 * j] = acc[i][j];
  }
}

// ---------------- fc_in combine (+ 3-level split of h0) ----------------
__global__ __launch_bounds__(256) void combine_fcin(
    const float* __restrict__ part, const float* __restrict__ b_fc,
    float* __restrict__ h, ushort* __restrict__ h1, ushort* __restrict__ h2,
    ushort* __restrict__ h3) {
  int idx = blockIdx.x * 256 + threadIdx.x;
  int j = idx & 1023; int b = idx >> 10;
  const size_t S = (size_t)BBATCH * HD;
  const float* p = part + (size_t)b * HD;
  float d = p[j]; d += p[S + j]; d += p[2 * S + j]; d += p[3 * S + j];
  float hv = d + b_fc[j];
  h[idx] = hv;
  ushort a = f2bf_rne(hv);
  float r1 = hv - bf2f(a);
  ushort bb = f2bf_rne(r1);
  float r2 = r1 - bf2f(bb);
  h1[idx] = a; h2[idx] = bb; h3[idx] = f2bf_rne(r2);
}

// ---------------- fused GRU: 32 steps in one persistent kernel -------------
// 384 blocks: colTile = bid>>1 (32 cols of GATE6), ksplit = bid&1 (512 K rows).
// Per step: phase G (MFMA GEMM, identical to R4 gru_gemm) -> grid barrier ->
// phase E (gate elementwise, identical to R4 gru_gate2) -> grid barrier.
__global__ __launch_bounds__(256, 2) void gru_fused(
    const ushort* __restrict__ W1, const ushort* __restrict__ W2,
    const ushort* __restrict__ W3,
    const float* __restrict__ b_ih, const float* __restrict__ b_hh,
    float* __restrict__ h, float* __restrict__ outs,
    ushort* __restrict__ outs_bf,
    ushort* __restrict__ h1, ushort* __restrict__ h2, ushort* __restrict__ h3,
    float* __restrict__ g2, u32* __restrict__ bar) {
  __shared__ ushort A1s[64 * 64], A2s[64 * 64], A3s[64 * 64];  // 8 KB each
  __shared__ ushort B1s[32 * 64], B2s[32 * 64], B3s[32 * 64];  // 4 KB each
  const int tid = threadIdx.x;
  const int lane = tid & 63, wid = tid >> 6;
  const int wr = wid >> 1, wc = wid & 1;
  const int bid = blockIdx.x;
  const int n0 = (bid >> 1) * 32;
  const int ksplit = bid & 1;
  const int kb0 = ksplit * 512;
  const ushort* B1g = W1 + (size_t)n0 * HD;
  const ushort* B2g = W2 + (size_t)n0 * HD;
  const ushort* B3g = W3 + (size_t)n0 * HD;
  const int rc = lane >> 3;
  const int gr8 = ((lane & 7) ^ rc) * 8;
  const int l15 = lane & 15;
  const int kseg = (lane >> 4) * 16;
  const int gidx = bid * 256 + tid;            // gate-phase element
  const size_t S = (size_t)BBATCH * GATE6;

  for (int t = 0; t < TSTEP; ++t) {
    // ---- phase G: g2[ksplit][64][n0..n0+32) = h @ W^T (cols n0..) ----
    if (t > 0 || n0 >= 3072) {
      f32x4 acc[2];
      acc[0] = (f32x4){0.f, 0.f, 0.f, 0.f};
      acc[1] = (f32x4){0.f, 0.f, 0.f, 0.f};
      for (int kt = 0; kt < 8; ++kt) {
        const int k0 = kb0 + kt * 64;
#pragma unroll
        for (int c = 0; c < 9; ++c) {
          int q = wid * 9 + c;
          const ushort* src; ushort* dst; int cl;
          if (q < 8)       { cl = q;      src = h1 + (size_t)(cl*8+rc) * HD;  dst = A1s + cl*512; }
          else if (q < 16) { cl = q - 8;  src = h2 + (size_t)(cl*8+rc) * HD;  dst = A2s + cl*512; }
          else if (q < 24) { cl = q - 16; src = h3 + (size_t)(cl*8+rc) * HD;  dst = A3s + cl*512; }
          else if (q < 28) { cl = q - 24; src = B1g + (size_t)(cl*8+rc) * HD; dst = B1s + cl*512; }
          else if (q < 32) { cl = q - 28; src = B2g + (size_t)(cl*8+rc) * HD; dst = B2s + cl*512; }
          else             { cl = q - 32; src = B3g + (size_t)(cl*8+rc) * HD; dst = B3s + cl*512; }
          gload16(src + k0 + gr8, dst);
        }
        asm volatile("s_waitcnt vmcnt(0)" ::: "memory");
        __syncthreads();
#pragma unroll
        for (int ks = 0; ks < 2; ++ks) {
          const int kb = ks * 64 + kseg;
          bf16x8 a1[2], a2[2], a3[2], b1, b2, b3;
#pragma unroll
          for (int m = 0; m < 2; ++m) {
            int row = wr * 32 + m * 16 + l15;
            int off = row * 128 + (kb ^ ((row & 7) << 4));
            a1[m] = *(const bf16x8*)((const char*)A1s + off);
            a2[m] = *(const bf16x8*)((const char*)A2s + off);
            a3[m] = *(const bf16x8*)((const char*)A3s + off);
          }
          {
            int row = wc * 16 + l15;
            int off = row * 128 + (kb ^ ((row & 7) << 4));
            b1 = *(const bf16x8*)((const char*)B1s + off);
            b2 = *(const bf16x8*)((const char*)B2s + off);
            b3 = *(const bf16x8*)((const char*)B3s + off);
          }
#pragma unroll
          for (int m = 0; m < 2; ++m) {
            acc[m] = __builtin_amdgcn_mfma_f32_16x16x32_bf16(a3[m], b1, acc[m], 0, 0, 0);
            acc[m] = __builtin_amdgcn_mfma_f32_16x16x32_bf16(a1[m], b3, acc[m], 0, 0, 0);
            acc[m] = __builtin_amdgcn_mfma_f32_16x16x32_bf16(a2[m], b2, acc[m], 0, 0, 0);
            acc[m] = __builtin_amdgcn_mfma_f32_16x16x32_bf16(a2[m], b1, acc[m], 0, 0, 0);
            acc[m] = __builtin_amdgcn_mfma_f32_16x16x32_bf16(a1[m], b2, acc[m], 0, 0, 0);
            acc[m] = __builtin_amdgcn_mfma_f32_16x16x32_bf16(a1[m], b1, acc[m], 0, 0, 0);
          }
        }
        __syncthreads();
      }
      float* G = g2 + (size_t)ksplit * BBATCH * GATE6;
#pragma unroll
      for (int m = 0; m < 2; ++m)
#pragma unroll
        for (int j = 0; j < 4; ++j) {
          int row = wr * 32 + m * 16 + (lane >> 4) * 4 + j;
          int col = n0 + wc * 16 + l15;
          G[(size_t)row * GATE6 + col] = acc[m][j];
        }
    }
    grid_bar2(bar, GRU_BLOCKS / 8);

    // ---- phase E: gate math for 65536 elements ----
    if (gidx < BBATCH * HD) {
      int b = gidx >> 10, j = gidx & 1023;
      const float* p = g2 + (size_t)b * GATE6;
      float gir, giz, gin;
      if (t == 0) {
        gir = b_ih[j]; giz = b_ih[HD + j]; gin = b_ih[2 * HD + j];
      } else {
        gir = p[j]        + p[S + j]        + b_ih[j];
        giz = p[HD + j]   + p[S + HD + j]   + b_ih[HD + j];
        gin = p[2*HD + j] + p[S + 2*HD + j] + b_ih[2 * HD + j];
      }
      float ghr = p[3072 + j]        + p[S + 3072 + j]        + b_hh[j];
      float ghz = p[3072 + HD + j]   + p[S + 3072 + HD + j]   + b_hh[HD + j];
      float ghn = p[3072 + 2*HD + j] + p[S + 3072 + 2*HD + j] + b_hh[2 * HD + j];
      float r = 1.0f / (1.0f + expf(-(gir + ghr)));
      float z = 1.0f / (1.0f + expf(-(giz + ghz)));
      float n = tanhf(gin + r * ghn);
      float hp = h[gidx];
      float hn = (1.0f - z) * n + z * hp;
      h[gidx] = hn;
      size_t o = ((size_t)t * BBATCH + b) * HD + j;
      outs[o] = hn;
      ushort a = f2bf_rne(hn);
      outs_bf[o] = a;
      float r1 = hn - bf2f(a);
      ushort bb = f2bf_rne(r1);
      float r2 = r1 - bf2f(bb);
      h1[gidx] = a; h2[gidx] = bb; h3[gidx] = f2bf_rne(r2);
    }
    grid_bar2(bar, GRU_BLOCKS / 8);
  }
}

// ---------------- bf16 MFMA fc_out prefilter, 2-phase pipelined ------------
// grid (2 row-halves, 250 col-blocks); 8 row-tiles of 128 per block.
// BK=32 double-buffered staging; swizzle: phys granule = g ^ ((row>>1)&3).
__global__ __launch_bounds__(256) void gemm_out_mfma(
    const ushort* __restrict__ Abf, const ushort* __restrict__ Bbf,
    const float* __restrict__ b_out, u64* __restrict__ keys) {
  __shared__ ushort Ab0[128 * 32], Ab1[128 * 32];   // 8 KB each
  __shared__ ushort Bb0[128 * 32], Bb1[128 * 32];
  __shared__ float Cs[32 * 133];
  __shared__ u64 pk[64 * 4];

  const int tid = threadIdx.x;
  const int lane = tid & 63;
  const int wid = tid >> 6;
  const int wr = wid >> 1, wc = wid & 1;
  const int cb = blockIdx.y;
  const int half = blockIdx.x;
  const int n0 = cb * 128;

  const ushort* Bg = Bbf + (size_t)n0 * HD;
  // staging: chunk = 16 rows x 32 k (1 KB); lane -> row chunk*16+(l>>2),
  // src granule = (l&3) ^ ((l>>3)&3)  [inverse of read swizzle]
  const int rc4 = lane >> 2;
  const int gs8 = ((lane & 3) ^ ((lane >> 3) & 3)) * 8;
  // read: logical granule q=lane>>4 of row R -> byte R*64 + ((q^((R>>1)&3))<<4)
  const int l15 = lane & 15;
  const int swoff = (((lane >> 4) ^ ((l15 >> 1) & 3)) << 4);

#define STAGE_OUT(AB, BB, k0) do {                                   \
    _Pragma("unroll")                                                \
    for (int c_ = 0; c_ < 2; ++c_) {                                 \
      int ch_ = wid * 2 + c_;                                        \
      int row_ = ch_ * 16 + rc4;                                     \
      gload16(Ag + (size_t)row_ * HD + (k0) + gs8, (AB) + ch_ * 512);\
      gload16(Bg + (size_t)row_ * HD + (k0) + gs8, (BB) + ch_ * 512);\
    }                                                                \
  } while (0)

#define COMPUTE_OUT(AB, BB) do {                                     \
    bf16x8 a_[4], b_[4];                                             \
    _Pragma("unroll")                                                \
    for (int m_ = 0; m_ < 4; ++m_)                                   \
      a_[m_] = *(const bf16x8*)((const char*)(AB) +                  \
               (wr * 64 + m_ * 16 + l15) * 64 + swoff);              \
    _Pragma("unroll")                                                \
    for (int n_ = 0; n_ < 4; ++n_)                                   \
      b_[n_] = *(const bf16x8*)((const char*)(BB) +                  \
               (wc * 64 + n_ * 16 + l15) * 64 + swoff);              \
    _Pragma("unroll")                                                \
    for (int m_ = 0; m_ < 4; ++m_)                                   \
      _Pragma("unroll")                                              \
      for (int n_ = 0; n_ < 4; ++n_)                                 \
        acc[m_][n_] = __builtin_amdgcn_mfma_f32_16x16x32_bf16(       \
            a_[m_], b_[n_], acc[m_][n_], 0, 0, 0);                   \
  } while (0)

  float bo[4];
#pragma unroll
  for (int n = 0; n < 4; ++n) bo[n] = b_out[n0 + wc * 64 + n * 16 + l15];

  for (int rb = 0; rb < 8; ++rb) {
    const int r0 = (half * 8 + rb) * 128;
    const ushort* Ag = Abf + (size_t)r0 * HD;

    f32x4 acc[4][4];
#pragma unroll
    for (int m = 0; m < 4; ++m)
#pragma unroll
      for (int n = 0; n < 4; ++n) acc[m][n] = (f32x4){0.f, 0.f, 0.f, 0.f};

    STAGE_OUT(Ab0, Bb0, 0);
    asm volatile("s_waitcnt vmcnt(0)" ::: "memory");
    __syncthreads();
    for (int kp = 0; kp < 16; ++kp) {
      STAGE_OUT(Ab1, Bb1, (2 * kp + 1) * 32);
      COMPUTE_OUT(Ab0, Bb0);
      asm volatile("s_waitcnt vmcnt(0)" ::: "memory");
      __syncthreads();
      if (kp < 15) STAGE_OUT(Ab0, Bb0, (2 * kp + 2) * 32);
      COMPUTE_OUT(Ab1, Bb1);
      asm volatile("s_waitcnt vmcnt(0)" ::: "memory");
      __syncthreads();
    }

    // epilogue: 4 quarters of 32 rows; per row top-4 keys over this 128-col slice
    for (int q = 0; q < 4; ++q) {
      if (wr == (q >> 1)) {
        int mbase = (q & 1) * 2;
#pragma unroll
        for (int mi = 0; mi < 2; ++mi) {
          int m = mbase + mi;
#pragma unroll
          for (int n = 0; n < 4; ++n) {
            int c = wc * 64 + n * 16 + l15;
#pragma unroll
            for (int j = 0; j < 4; ++j) {
              int lr = mi * 16 + (lane >> 4) * 4 + j;
              Cs[lr * 133 + c] = acc[m][n][j] + bo[n];
            }
          }
        }
      }
      __syncthreads();
      if (tid < 64) {
        int rr = tid >> 1, hc = (tid & 1) * 64;
        const float* rp = Cs + rr * 133 + hc;
        u64 t4[4] = {0, 0, 0, 0};
        for (int c = 0; c < 64; ++c) insert4(t4, packkey(rp[c], n0 + hc + c));
        u64* d = pk + tid * 4;
        d[0] = t4[0]; d[1] = t4[1]; d[2] = t4[2]; d[3] = t4[3];
      }
      __syncthreads();
      if (tid < 32) {
        const u64* a4 = pk + tid * 8;
        u64 t4[4] = {a4[0], a4[1], a4[2], a4[3]};
        insert4(t4, a4[4]); insert4(t4, a4[5]); insert4(t4, a4[6]); insert4(t4, a4[7]);
        int grow = r0 + q * 32 + tid;
        u64* kp2 = keys + ((size_t)grow * NCB + cb) * 4;
        kp2[0] = t4[0]; kp2[1] = t4[1]; kp2[2] = t4[2]; kp2[3] = t4[3];
      }
      __syncthreads();
    }
  }
#undef STAGE_OUT
#undef COMPUTE_OUT
}

// ---------------- per-row: top-16 -> fp32 rescore -> top-8 -> sample ------
__global__ __launch_bounds__(256) void merge_sample2(
    const u64* __restrict__ keys, const float* __restrict__ outs,
    const float* __restrict__ W_out, const float* __restrict__ b_out,
    int* __restrict__ out) {
  const int r = blockIdx.x, tid = threadIdx.x;
  const int lane = tid & 63, wid = tid >> 6;
  __shared__ u64 K[1000];
  __shared__ u64 wmax[4];
  __shared__ u64 topw[NCAND];
  __shared__ float candv[NCAND];
  __shared__ float row_f[1024];
  for (int i = tid; i < 1000; i += 256) K[i] = keys[(size_t)r * 1000 + i];
  for (int i = tid; i < 1024; i += 256) row_f[i] = outs[(size_t)r * 1024 + i];
  __syncthreads();
  for (int it = 0; it < NCAND; ++it) {
    u64 b = 0;
#pragma unroll
    for (int l = 0; l < 4; ++l) {
      int i = tid + l * 256;
      if (i < 1000) { u64 v = K[i]; b = (v > b) ? v : b; }
    }
#pragma unroll
    for (int o = 32; o; o >>= 1) {
      u64 x = __shfl_xor(b, o);
      if (x > b) b = x;
    }
    if (lane == 0) wmax[wid] = b;
    __syncthreads();
    u64 w = wmax[0];
    if (wmax[1] > w) w = wmax[1];
    if (wmax[2] > w) w = wmax[2];
    if (wmax[3] > w) w = wmax[3];
    if (tid == 0) topw[it] = w;
#pragma unroll
    for (int l = 0; l < 4; ++l) {
      int i = tid + l * 256;
      if (i < 1000 && K[i] == w) K[i] = 0;
    }
    __syncthreads();
  }
  {
    int c = tid >> 4, l16 = tid & 15;
    int vidx = (int)(~(u32)(topw[c] & 0xffffffffu));
    const float* wrow = W_out + (size_t)vidx * HD;
    float s = 0.f;
    for (int e = l16; e < 1024; e += 16) s += row_f[e] * wrow[e];
#pragma unroll
    for (int o = 8; o; o >>= 1) s += __shfl_xor(s, o, 16);
    if (l16 == 0) candv[c] = s + b_out[vidx];
  }
  __syncthreads();
  if (tid == 0) {
    float v[NCAND]; int vi[NCAND];
#pragma unroll
    for (int q = 0; q < NCAND; ++q) {
      v[q] = candv[q];
      vi[q] = (int)(~(u32)(topw[q] & 0xffffffffu));
    }
    for (int a = 0; a < 8; ++a)
      for (int b2 = a + 1; b2 < NCAND; ++b2) {
        bool sw = (v[b2] > v[a]) || (v[b2] == v[a] && vi[b2] < vi[a]);
        if (sw) {
          float tf = v[a]; v[a] = v[b2]; v[b2] = tf;
          int ti = vi[a]; vi[a] = vi[b2]; vi[b2] = ti;
        }
      }
    const float M = v[0];
    const float TINY = 1.17549435e-38f;
    float best = -3.4e38f; int bi = 0;
    for (int k = 0; k < 8; ++k) {
      float lp = v[k] - M;
      u32 bits = jax_random_bits((u32)(r * 8 + k));
      float f = __uint_as_float((bits >> 9) | 0x3f800000u) - 1.0f;
      float u = f * (1.0f - TINY) + TINY;
      u = fmaxf(TINY, u);
      float g = -logf(-logf(u));
      float s = g + lp;
      if (s > best) { best = s; bi = k; }
    }
    int t = r >> 6, b = r & 63;
    out[b * TSTEP + t] = vi[bi];
  }
}

extern "C" void kernel_launch(void* const* d_in, const int* in_sizes, int n_in,
                              void* d_out, int out_size, void* d_ws, size_t ws_size,
                              hipStream_t stream) {
  (void)in_sizes; (void)n_in; (void)out_size; (void)ws_size;
  const float* vectors = (const float*)d_in[0];
  const float* W_fc_in = (const float*)d_in[1];
  const float* b_fc_in = (const float*)d_in[2];
  const float* W_ih    = (const float*)d_in[3];
  const float* W_hh    = (const float*)d_in[4];
  const float* b_ih    = (const float*)d_in[5];
  const float* b_hh    = (const float*)d_in[6];
  const float* W_out   = (const float*)d_in[7];
  const float* b_out   = (const float*)d_in[8];
  int* out = (int*)d_out;

  char* w = (char*)d_ws;
  float* h = (float*)w;          w += (size_t)BBATCH * HD * 4;        // 256 KB
  float* outs = (float*)w;       w += (size_t)NROWS * HD * 4;         // 8 MB
  ushort* outs_bf = (ushort*)w;  w += (size_t)NROWS * HD * 2;         // 4 MB
  ushort* Wbf = (ushort*)w;      w += (size_t)VOCAB * HD * 2;         // 65.5 MB
  // X region: Wg 3-level splits live through the fused GRU; keys (16 MB)
  // aliases it afterwards (prefilter runs after the GRU kernel).
  char* X = w;                   w += (size_t)3 * GATE6 * HD * 2;     // 37.75 MB
  ushort* Wg1 = (ushort*)X;
  ushort* Wg2 = Wg1 + (size_t)GATE6 * HD;
  ushort* Wg3 = Wg2 + (size_t)GATE6 * HD;
  u64* keys = (u64*)X;                                               // alias
  ushort* h1 = (ushort*)w;       w += (size_t)BBATCH * HD * 2;        // 128 KB
  ushort* h2 = (ushort*)w;       w += (size_t)BBATCH * HD * 2;        // 128 KB
  ushort* h3 = (ushort*)w;       w += (size_t)BBATCH * HD * 2;        // 128 KB
  u32* bar = (u32*)w;            w += 4096;                           // barrier state
  float* part = (float*)w;       // fc_in partials: 4*64*1024 fp32 = 1 MB
  float* g2   = (float*)w;       // GRU partials:   2*64*6144 fp32 = 3.1 MB

  // zero barrier state (graph-capturable async memset)
  hipMemsetAsync(bar, 0, 4096, stream);

  // one-time weight conversions
  tobf16<<<4096, 256, 0, stream>>>(W_out, Wbf, VOCAB * HD / 8);
  tobf16x3_gru<<<1024, 256, 0, stream>>>(W_ih, W_hh, Wg1, Wg2, Wg3, GATE6 * HD / 8);

  // fc_in: h0 = vectors @ W_fc_in^T + b_fc_in  (fp32, split-K=4)
  gemm64_nt<<<dim3(32, 4), 256, 0, stream>>>(vectors, W_fc_in, part);
  combine_fcin<<<256, 256, 0, stream>>>(part, b_fc_in, h, h1, h2, h3);

  // all 32 GRU steps in one persistent kernel (R4 numerics preserved)
  gru_fused<<<GRU_BLOCKS, 256, 0, stream>>>(Wg1, Wg2, Wg3, b_ih, b_hh,
                                            h, outs, outs_bf, h1, h2, h3,
                                            g2, bar);

  // bf16 MFMA prefilter over the vocab (2-phase pipelined)
  gemm_out_mfma<<<dim3(2, NCB), 256, 0, stream>>>(outs_bf, Wbf, b_out, keys);

  // exact fp32 rescore of top-16 + Threefry/Gumbel sampling
  merge_sample2<<<NROWS, 256, 0, stream>>>(keys, outs, W_out, b_out, out);
}

// Round 6
// 1529.993 us; speedup vs baseline: 3.1472x; 3.1472x over previous
//
#include <hip/hip_runtime.h>
#include <stdint.h>

typedef unsigned int u32;
typedef unsigned long long u64;
typedef unsigned short ushort;
typedef __attribute__((ext_vector_type(8))) short bf16x8;
typedef __attribute__((ext_vector_type(4))) float f32x4;

#define JAX_PARTITIONABLE 1

#define HD     1024
#define BBATCH 64
#define TSTEP  32
#define VOCAB  32000
#define NROWS  2048      // TSTEP * BBATCH
#define GATE6  6144      // 6 * HD
#define NCB    250       // 32000 / 128 col-blocks
#define NCAND  16
#define GBLK   128       // GRU j-slice blocks (8 cols each, 48 W' rows)

// ---------------- Threefry-2x32 (matches jax._src.prng) ----------------
__device__ __forceinline__ void threefry2x32(u32 k0, u32 k1, u32 x0, u32 x1,
                                             u32& y0, u32& y1) {
  u32 ks2 = k0 ^ k1 ^ 0x1BD11BDAu;
  x0 += k0; x1 += k1;
#define TFR(r) do { x0 += x1; x1 = (x1 << (r)) | (x1 >> (32 - (r))); x1 ^= x0; } while (0)
  TFR(13); TFR(15); TFR(26); TFR(6);   x0 += k1;  x1 += ks2 + 1u;
  TFR(17); TFR(29); TFR(16); TFR(24);  x0 += ks2; x1 += k0 + 2u;
  TFR(13); TFR(15); TFR(26); TFR(6);   x0 += k0;  x1 += k1 + 3u;
  TFR(17); TFR(29); TFR(16); TFR(24);  x0 += k1;  x1 += ks2 + 4u;
  TFR(13); TFR(15); TFR(26); TFR(6);   x0 += ks2; x1 += k0 + 5u;
#undef TFR
  y0 = x0; y1 = x1;
}

__device__ __forceinline__ u32 jax_random_bits(u32 n) {
#if JAX_PARTITIONABLE
  u32 y0, y1; threefry2x32(0u, 42u, 0u, n, y0, y1);
  return y0 ^ y1;
#else
  u32 y0, y1;
  if (n < 8192u) { threefry2x32(0u, 42u, n, n + 8192u, y0, y1); return y0; }
  else           { threefry2x32(0u, 42u, n - 8192u, n, y0, y1); return y1; }
#endif
}

// value-desc, tie -> lower vocab index wins
__device__ __forceinline__ u64 packkey(float v, int idx) {
  u32 b = __float_as_uint(v);
  b = (b & 0x80000000u) ? ~b : (b | 0x80000000u);
  return ((u64)b << 32) | (u64)(~(u32)idx);
}

__device__ __forceinline__ void insert4(u64* t4, u64 k) {
  if (k > t4[3]) {
    t4[3] = k;
    if (t4[3] > t4[2]) { u64 tm = t4[2]; t4[2] = t4[3]; t4[3] = tm; }
    if (t4[2] > t4[1]) { u64 tm = t4[1]; t4[1] = t4[2]; t4[2] = tm; }
    if (t4[1] > t4[0]) { u64 tm = t4[0]; t4[0] = t4[1]; t4[1] = tm; }
  }
}

__device__ __forceinline__ ushort f2bf_rne(float x) {
  u32 u = __float_as_uint(x);
  return (ushort)((u + 0x7fffu + ((u >> 16) & 1u)) >> 16);
}
__device__ __forceinline__ float bf2f(ushort h) {
  return __uint_as_float(((u32)h) << 16);
}

typedef const __attribute__((address_space(1))) void* gas_ptr;
typedef __attribute__((address_space(3))) void* las_ptr;
__device__ __forceinline__ void gload16(const void* g, void* l) {
  __builtin_amdgcn_global_load_lds((gas_ptr)g, (las_ptr)l, 16, 0, 0);
}

// ---------------- fp32 -> bf16 bulk convert ----------------
__global__ __launch_bounds__(256) void tobf16(const float* __restrict__ src,
                                              ushort* __restrict__ dst, int n8) {
  int i = blockIdx.x * 256 + threadIdx.x;
  const int stride = gridDim.x * 256;
  for (; i < n8; i += stride) {
    const float4* s4 = (const float4*)src + (size_t)i * 2;
    float4 a = s4[0], b = s4[1];
    u32 o0 = f2bf_rne(a.x) | ((u32)f2bf_rne(a.y) << 16);
    u32 o1 = f2bf_rne(a.z) | ((u32)f2bf_rne(a.w) << 16);
    u32 o2 = f2bf_rne(b.x) | ((u32)f2bf_rne(b.y) << 16);
    u32 o3 = f2bf_rne(b.z) | ((u32)f2bf_rne(b.w) << 16);
    ((uint4*)dst)[i] = make_uint4(o0, o1, o2, o3);
  }
}

// ------- W_ih|W_hh -> PERMUTED bf16 3-level split for block-local gates ----
// out row r' = b*48 + g*8 + j'  (b=0..127, g=0..5, j'=0..7)
// src row    = (g<3 ? W_ih row g*1024 + b*8+j' : W_hh row (g-3)*1024 + b*8+j')
__global__ __launch_bounds__(256) void tobf16x3_gruP(
    const float* __restrict__ Wih, const float* __restrict__ Whh,
    ushort* __restrict__ w1, ushort* __restrict__ w2, ushort* __restrict__ w3) {
  int i = blockIdx.x * 256 + threadIdx.x;   // 6144 * 128 threads, 8 elems each
  if (i >= GATE6 * (HD / 8)) return;
  int rp = i >> 7;           // out row
  int kc = i & 127;          // 8-elem chunk along K
  int b = rp / 48, rem = rp % 48;
  int g = rem >> 3, jp = rem & 7;
  const float* src = (g < 3)
      ? (Wih + ((size_t)g * HD + b * 8 + jp) * HD)
      : (Whh + ((size_t)(g - 3) * HD + b * 8 + jp) * HD);
  const float4* s4 = (const float4*)(src + kc * 8);
  float v[8];
  float4 a = s4[0], bb = s4[1];
  v[0]=a.x; v[1]=a.y; v[2]=a.z; v[3]=a.w; v[4]=bb.x; v[5]=bb.y; v[6]=bb.z; v[7]=bb.w;
  ushort p1[8], p2[8], p3[8];
#pragma unroll
  for (int e = 0; e < 8; ++e) {
    p1[e] = f2bf_rne(v[e]);
    float r1 = v[e] - bf2f(p1[e]);
    p2[e] = f2bf_rne(r1);
    float r2 = r1 - bf2f(p2[e]);
    p3[e] = f2bf_rne(r2);
  }
  u32 o1[4], o2[4], o3[4];
#pragma unroll
  for (int e = 0; e < 4; ++e) {
    o1[e] = p1[2*e] | ((u32)p1[2*e+1] << 16);
    o2[e] = p2[2*e] | ((u32)p2[2*e+1] << 16);
    o3[e] = p3[2*e] | ((u32)p3[2*e+1] << 16);
  }
  ((uint4*)w1)[i] = make_uint4(o1[0], o1[1], o1[2], o1[3]);
  ((uint4*)w2)[i] = make_uint4(o2[0], o2[1], o2[2], o2[3]);
  ((uint4*)w3)[i] = make_uint4(o3[0], o3[1], o3[2], o3[3]);
}

// ---------------- fc_in skinny NT GEMM (fp32, one-time) ----------------
__global__ __launch_bounds__(256) void gemm64_nt(
    const float* __restrict__ A, const float* __restrict__ B,
    float* __restrict__ part) {
  __shared__ float4 As4[64 * 33];
  __shared__ float4 Bs4[32 * 33];
  const int tid = threadIdx.x;
  const int n0 = blockIdx.x * 32;
  const float* Brow = B + (size_t)n0 * HD;
  const int ks = blockIdx.y * 256;
  const int tc = tid & 7, trg = tid >> 3;
  float acc[2][4] = {};
  for (int kc = 0; kc < 2; ++kc) {
    const int k0 = ks + kc * 128;
#pragma unroll
    for (int l = 0; l < 8; ++l) {
      int m = tid + l * 256; int row = m >> 5, k4 = m & 31;
      As4[row * 33 + k4] = *(const float4*)(A + (size_t)row * HD + k0 + k4 * 4);
    }
#pragma unroll
    for (int l = 0; l < 4; ++l) {
      int m = tid + l * 256; int row = m >> 5, k4 = m & 31;
      Bs4[row * 33 + k4] = *(const float4*)(Brow + (size_t)row * HD + k0 + k4 * 4);
    }
    __syncthreads();
#pragma unroll
    for (int kq = 0; kq < 32; ++kq) {
      float4 av[2], bv[4];
      av[0] = As4[trg * 33 + kq];
      av[1] = As4[(trg + 32) * 33 + kq];
      bv[0] = Bs4[tc * 33 + kq];
      bv[1] = Bs4[(tc + 8) * 33 + kq];
      bv[2] = Bs4[(tc + 16) * 33 + kq];
      bv[3] = Bs4[(tc + 24) * 33 + kq];
#pragma unroll
      for (int i = 0; i < 2; ++i)
#pragma unroll
        for (int j = 0; j < 4; ++j) {
          acc[i][j] += av[i].x * bv[j].x;
          acc[i][j] += av[i].y * bv[j].y;
          acc[i][j] += av[i].z * bv[j].z;
          acc[i][j] += av[i].w * bv[j].w;
        }
    }
    __syncthreads();
  }
  float* P = part + (size_t)blockIdx.y * BBATCH * HD;
#pragma unroll
  for (int i = 0; i < 2; ++i) {
    int b = trg + 32 * i;
#pragma unroll
    for (int j = 0; j < 4; ++j)
      P[(size_t)b * HD + n0 + tc + 8 * j] = acc[i][j];
  }
}

// ---------------- fc_in combine (+ 3-level split of h0) ----------------
__global__ __launch_bounds__(256) void combine_fcin(
    const float* __restrict__ part, const float* __restrict__ b_fc,
    float* __restrict__ h, ushort* __restrict__ h1, ushort* __restrict__ h2,
    ushort* __restrict__ h3) {
  int idx = blockIdx.x * 256 + threadIdx.x;
  int j = idx & 1023; int b = idx >> 10;
  const size_t S = (size_t)BBATCH * HD;
  const float* p = part + (size_t)b * HD;
  float d = p[j]; d += p[S + j]; d += p[2 * S + j]; d += p[3 * S + j];
  float hv = d + b_fc[j];
  h[idx] = hv;
  ushort a = f2bf_rne(hv);
  float r1 = hv - bf2f(a);
  ushort bb = f2bf_rne(r1);
  float r2 = r1 - bf2f(bb);
  h1[idx] = a; h2[idx] = bb; h3[idx] = f2bf_rne(r2);
}

// ---------------- GRU one step: GEMM + in-register gate, no exchange -------
// 128 blocks; block b owns j in [b*8, b*8+8) across ALL 6 gates (W' rows
// b*48..b*48+48). 4 waves: wave w = batch rows [w*16, w*16+16). K=1024 full.
// LDS: A = h splits 64x64x3 (24 KB), B = W' 48x64x3 (18 KB) per K-chunk.
__global__ __launch_bounds__(256) void gru_step(
    const ushort* __restrict__ W1, const ushort* __restrict__ W2,
    const ushort* __restrict__ W3,
    const float* __restrict__ b_ih, const float* __restrict__ b_hh,
    float* __restrict__ h, float* __restrict__ outs,
    ushort* __restrict__ outs_bf,
    ushort* __restrict__ h1, ushort* __restrict__ h2, ushort* __restrict__ h3,
    int t) {
  __shared__ ushort S[21504];   // A: 3*4096 ushorts @0; B: 3*3072 @12288
  const int tid = threadIdx.x;
  const int lane = tid & 63, wid = tid >> 6;
  const int b = blockIdx.x;
  const ushort* B1g = W1 + (size_t)b * 48 * HD;
  const ushort* B2g = W2 + (size_t)b * 48 * HD;
  const ushort* B3g = W3 + (size_t)b * 48 * HD;
  const int rc = lane >> 3;
  const int gr8 = ((lane & 7) ^ rc) * 8;
  const int l15 = lane & 15;
  const int kseg = (lane >> 4) * 16;

  f32x4 acc[3];
#pragma unroll
  for (int nt = 0; nt < 3; ++nt) acc[nt] = (f32x4){0.f, 0.f, 0.f, 0.f};

  for (int kt = 0; kt < 16; ++kt) {
    const int k0 = kt * 64;
    // 42 chunks: A = 24 (3 levels x 8), B = 18 (3 levels x 6); wave w: 11
#pragma unroll
    for (int c = 0; c < 11; ++c) {
      int q = wid * 11 + c;
      if (q < 42) {
        const ushort* src; ushort* dst;
        if (q < 24) {
          int lv = q >> 3, cl = q & 7;
          src = (lv == 0 ? h1 : lv == 1 ? h2 : h3) + (size_t)(cl * 8 + rc) * HD;
          dst = S + lv * 4096 + cl * 512;
        } else {
          int q2 = q - 24; int lv = q2 / 6, cl = q2 % 6;
          src = (lv == 0 ? B1g : lv == 1 ? B2g : B3g) + (size_t)(cl * 8 + rc) * HD;
          dst = S + 12288 + lv * 3072 + cl * 512;
        }
        gload16(src + k0 + gr8, dst);
      }
    }
    asm volatile("s_waitcnt vmcnt(0)" ::: "memory");
    __syncthreads();
#pragma unroll
    for (int ks = 0; ks < 2; ++ks) {
      const int kb = ks * 64 + kseg;
      const int ar = wid * 16 + l15;
      const int aoff = ar * 128 + (kb ^ ((ar & 7) << 4));
      bf16x8 a1 = *(const bf16x8*)((const char*)S + aoff);
      bf16x8 a2 = *(const bf16x8*)((const char*)S + 8192 + aoff);
      bf16x8 a3 = *(const bf16x8*)((const char*)S + 16384 + aoff);
      bf16x8 b1[3], b2[3], b3[3];
#pragma unroll
      for (int nt = 0; nt < 3; ++nt) {
        int br = nt * 16 + l15;
        int boff = br * 128 + (kb ^ ((br & 7) << 4));
        b1[nt] = *(const bf16x8*)((const char*)S + 24576 + boff);
        b2[nt] = *(const bf16x8*)((const char*)S + 30720 + boff);
        b3[nt] = *(const bf16x8*)((const char*)S + 36864 + boff);
      }
#pragma unroll
      for (int nt = 0; nt < 3; ++nt) {
        acc[nt] = __builtin_amdgcn_mfma_f32_16x16x32_bf16(a3, b1[nt], acc[nt], 0, 0, 0);
        acc[nt] = __builtin_amdgcn_mfma_f32_16x16x32_bf16(a1, b3[nt], acc[nt], 0, 0, 0);
        acc[nt] = __builtin_amdgcn_mfma_f32_16x16x32_bf16(a2, b2[nt], acc[nt], 0, 0, 0);
        acc[nt] = __builtin_amdgcn_mfma_f32_16x16x32_bf16(a2, b1[nt], acc[nt], 0, 0, 0);
        acc[nt] = __builtin_amdgcn_mfma_f32_16x16x32_bf16(a1, b2[nt], acc[nt], 0, 0, 0);
        acc[nt] = __builtin_amdgcn_mfma_f32_16x16x32_bf16(a1, b1[nt], acc[nt], 0, 0, 0);
      }
    }
    __syncthreads();
  }

  // ---- in-register gate math ----
  // C layout: col = nt*16 + l15, row = wid*16 + (lane>>4)*4 + reg.
  // col c in [0,48): gate g = c>>3, j' = c&7.  Low lanes (l15<8) hold
  // g={0,2,4} = ir,in,hz; partner lane (+8) holds g={1,3,5} = iz,hr,hn.
  const bool low = (l15 < 8);
  const int j = b * 8 + l15;         // valid for low lanes
  float bi_r = 0.f, bi_z = 0.f, bi_n = 0.f, bh_r = 0.f, bh_z = 0.f, bh_n = 0.f;
  if (low) {
    bi_r = b_ih[j]; bi_z = b_ih[HD + j]; bi_n = b_ih[2 * HD + j];
    bh_r = b_hh[j]; bh_z = b_hh[HD + j]; bh_n = b_hh[2 * HD + j];
  }
#pragma unroll
  for (int r = 0; r < 4; ++r) {
    float v0 = acc[0][r], v1 = acc[1][r], v2 = acc[2][r];
    float p0 = __shfl_xor(v0, 8);    // iz  (on low lanes)
    float p1 = __shfl_xor(v1, 8);    // hr
    float p2 = __shfl_xor(v2, 8);    // hn
    if (low) {
      float gir = (t == 0) ? bi_r : (v0 + bi_r);
      float giz = (t == 0) ? bi_z : (p0 + bi_z);
      float gin = (t == 0) ? bi_n : (v1 + bi_n);
      float ghr = p1 + bh_r;
      float ghz = v2 + bh_z;
      float ghn = p2 + bh_n;
      float rr = 1.0f / (1.0f + expf(-(gir + ghr)));
      float zz = 1.0f / (1.0f + expf(-(giz + ghz)));
      float nn = tanhf(gin + rr * ghn);
      int i = wid * 16 + (lane >> 4) * 4 + r;
      int idx = i * HD + j;
      float hp = h[idx];
      float hn2 = (1.0f - zz) * nn + zz * hp;
      h[idx] = hn2;
      size_t o = ((size_t)t * BBATCH + i) * HD + j;
      outs[o] = hn2;
      ushort a = f2bf_rne(hn2);
      outs_bf[o] = a;
      float r1 = hn2 - bf2f(a);
      ushort bb2 = f2bf_rne(r1);
      float r2 = r1 - bf2f(bb2);
      h1[idx] = a; h2[idx] = bb2; h3[idx] = f2bf_rne(r2);
    }
  }
}

// ---------------- bf16 MFMA fc_out prefilter, 2-phase pipelined ------------
__global__ __launch_bounds__(256) void gemm_out_mfma(
    const ushort* __restrict__ Abf, const ushort* __restrict__ Bbf,
    const float* __restrict__ b_out, u64* __restrict__ keys) {
  __shared__ ushort Ab0[128 * 32], Ab1[128 * 32];
  __shared__ ushort Bb0[128 * 32], Bb1[128 * 32];
  __shared__ float Cs[32 * 133];
  __shared__ u64 pk[64 * 4];

  const int tid = threadIdx.x;
  const int lane = tid & 63;
  const int wid = tid >> 6;
  const int wr = wid >> 1, wc = wid & 1;
  const int cb = blockIdx.y;
  const int half = blockIdx.x;
  const int n0 = cb * 128;

  const ushort* Bg = Bbf + (size_t)n0 * HD;
  const int rc4 = lane >> 2;
  const int gs8 = ((lane & 3) ^ ((lane >> 3) & 3)) * 8;
  const int l15 = lane & 15;
  const int swoff = (((lane >> 4) ^ ((l15 >> 1) & 3)) << 4);

#define STAGE_OUT(AB, BB, k0) do {                                   \
    _Pragma("unroll")                                                \
    for (int c_ = 0; c_ < 2; ++c_) {                                 \
      int ch_ = wid * 2 + c_;                                        \
      int row_ = ch_ * 16 + rc4;                                     \
      gload16(Ag + (size_t)row_ * HD + (k0) + gs8, (AB) + ch_ * 512);\
      gload16(Bg + (size_t)row_ * HD + (k0) + gs8, (BB) + ch_ * 512);\
    }                                                                \
  } while (0)

#define COMPUTE_OUT(AB, BB) do {                                     \
    bf16x8 a_[4], b_[4];                                             \
    _Pragma("unroll")                                                \
    for (int m_ = 0; m_ < 4; ++m_)                                   \
      a_[m_] = *(const bf16x8*)((const char*)(AB) +                  \
               (wr * 64 + m_ * 16 + l15) * 64 + swoff);              \
    _Pragma("unroll")                                                \
    for (int n_ = 0; n_ < 4; ++n_)                                   \
      b_[n_] = *(const bf16x8*)((const char*)(BB) +                  \
               (wc * 64 + n_ * 16 + l15) * 64 + swoff);              \
    _Pragma("unroll")                                                \
    for (int m_ = 0; m_ < 4; ++m_)                                   \
      _Pragma("unroll")                                              \
      for (int n_ = 0; n_ < 4; ++n_)                                 \
        acc[m_][n_] = __builtin_amdgcn_mfma_f32_16x16x32_bf16(       \
            a_[m_], b_[n_], acc[m_][n_], 0, 0, 0);                   \
  } while (0)

  float bo[4];
#pragma unroll
  for (int n = 0; n < 4; ++n) bo[n] = b_out[n0 + wc * 64 + n * 16 + l15];

  for (int rb = 0; rb < 8; ++rb) {
    const int r0 = (half * 8 + rb) * 128;
    const ushort* Ag = Abf + (size_t)r0 * HD;

    f32x4 acc[4][4];
#pragma unroll
    for (int m = 0; m < 4; ++m)
#pragma unroll
      for (int n = 0; n < 4; ++n) acc[m][n] = (f32x4){0.f, 0.f, 0.f, 0.f};

    STAGE_OUT(Ab0, Bb0, 0);
    asm volatile("s_waitcnt vmcnt(0)" ::: "memory");
    __syncthreads();
    for (int kp = 0; kp < 16; ++kp) {
      STAGE_OUT(Ab1, Bb1, (2 * kp + 1) * 32);
      COMPUTE_OUT(Ab0, Bb0);
      asm volatile("s_waitcnt vmcnt(0)" ::: "memory");
      __syncthreads();
      if (kp < 15) STAGE_OUT(Ab0, Bb0, (2 * kp + 2) * 32);
      COMPUTE_OUT(Ab1, Bb1);
      asm volatile("s_waitcnt vmcnt(0)" ::: "memory");
      __syncthreads();
    }

    for (int q = 0; q < 4; ++q) {
      if (wr == (q >> 1)) {
        int mbase = (q & 1) * 2;
#pragma unroll
        for (int mi = 0; mi < 2; ++mi) {
          int m = mbase + mi;
#pragma unroll
          for (int n = 0; n < 4; ++n) {
            int c = wc * 64 + n * 16 + l15;
#pragma unroll
            for (int j = 0; j < 4; ++j) {
              int lr = mi * 16 + (lane >> 4) * 4 + j;
              Cs[lr * 133 + c] = acc[m][n][j] + bo[n];
            }
          }
        }
      }
      __syncthreads();
      if (tid < 64) {
        int rr = tid >> 1, hc = (tid & 1) * 64;
        const float* rp = Cs + rr * 133 + hc;
        u64 t4[4] = {0, 0, 0, 0};
        for (int c = 0; c < 64; ++c) insert4(t4, packkey(rp[c], n0 + hc + c));
        u64* d = pk + tid * 4;
        d[0] = t4[0]; d[1] = t4[1]; d[2] = t4[2]; d[3] = t4[3];
      }
      __syncthreads();
      if (tid < 32) {
        const u64* a4 = pk + tid * 8;
        u64 t4[4] = {a4[0], a4[1], a4[2], a4[3]};
        insert4(t4, a4[4]); insert4(t4, a4[5]); insert4(t4, a4[6]); insert4(t4, a4[7]);
        int grow = r0 + q * 32 + tid;
        u64* kp2 = keys + ((size_t)grow * NCB + cb) * 4;
        kp2[0] = t4[0]; kp2[1] = t4[1]; kp2[2] = t4[2]; kp2[3] = t4[3];
      }
      __syncthreads();
    }
  }
#undef STAGE_OUT
#undef COMPUTE_OUT
}

// ---------------- per-row: top-16 -> fp32 rescore -> top-8 -> sample ------
__global__ __launch_bounds__(256) void merge_sample2(
    const u64* __restrict__ keys, const float* __restrict__ outs,
    const float* __restrict__ W_out, const float* __restrict__ b_out,
    int* __restrict__ out) {
  const int r = blockIdx.x, tid = threadIdx.x;
  const int lane = tid & 63, wid = tid >> 6;
  __shared__ u64 K[1000];
  __shared__ u64 wmax[4];
  __shared__ u64 topw[NCAND];
  __shared__ float candv[NCAND];
  __shared__ float row_f[1024];
  for (int i = tid; i < 1000; i += 256) K[i] = keys[(size_t)r * 1000 + i];
  for (int i = tid; i < 1024; i += 256) row_f[i] = outs[(size_t)r * 1024 + i];
  __syncthreads();
  for (int it = 0; it < NCAND; ++it) {
    u64 b = 0;
#pragma unroll
    for (int l = 0; l < 4; ++l) {
      int i = tid + l * 256;
      if (i < 1000) { u64 v = K[i]; b = (v > b) ? v : b; }
    }
#pragma unroll
    for (int o = 32; o; o >>= 1) {
      u64 x = __shfl_xor(b, o);
      if (x > b) b = x;
    }
    if (lane == 0) wmax[wid] = b;
    __syncthreads();
    u64 w = wmax[0];
    if (wmax[1] > w) w = wmax[1];
    if (wmax[2] > w) w = wmax[2];
    if (wmax[3] > w) w = wmax[3];
    if (tid == 0) topw[it] = w;
#pragma unroll
    for (int l = 0; l < 4; ++l) {
      int i = tid + l * 256;
      if (i < 1000 && K[i] == w) K[i] = 0;
    }
    __syncthreads();
  }
  {
    int c = tid >> 4, l16 = tid & 15;
    int vidx = (int)(~(u32)(topw[c] & 0xffffffffu));
    const float* wrow = W_out + (size_t)vidx * HD;
    float s = 0.f;
    for (int e = l16; e < 1024; e += 16) s += row_f[e] * wrow[e];
#pragma unroll
    for (int o = 8; o; o >>= 1) s += __shfl_xor(s, o, 16);
    if (l16 == 0) candv[c] = s + b_out[vidx];
  }
  __syncthreads();
  if (tid == 0) {
    float v[NCAND]; int vi[NCAND];
#pragma unroll
    for (int q = 0; q < NCAND; ++q) {
      v[q] = candv[q];
      vi[q] = (int)(~(u32)(topw[q] & 0xffffffffu));
    }
    for (int a = 0; a < 8; ++a)
      for (int b2 = a + 1; b2 < NCAND; ++b2) {
        bool sw = (v[b2] > v[a]) || (v[b2] == v[a] && vi[b2] < vi[a]);
        if (sw) {
          float tf = v[a]; v[a] = v[b2]; v[b2] = tf;
          int ti = vi[a]; vi[a] = vi[b2]; vi[b2] = ti;
        }
      }
    const float M = v[0];
    const float TINY = 1.17549435e-38f;
    float best = -3.4e38f; int bi = 0;
    for (int k = 0; k < 8; ++k) {
      float lp = v[k] - M;
      u32 bits = jax_random_bits((u32)(r * 8 + k));
      float f = __uint_as_float((bits >> 9) | 0x3f800000u) - 1.0f;
      float u = f * (1.0f - TINY) + TINY;
      u = fmaxf(TINY, u);
      float g = -logf(-logf(u));
      float s = g + lp;
      if (s > best) { best = s; bi = k; }
    }
    int t = r >> 6, b = r & 63;
    out[b * TSTEP + t] = vi[bi];
  }
}

extern "C" void kernel_launch(void* const* d_in, const int* in_sizes, int n_in,
                              void* d_out, int out_size, void* d_ws, size_t ws_size,
                              hipStream_t stream) {
  (void)in_sizes; (void)n_in; (void)out_size; (void)ws_size;
  const float* vectors = (const float*)d_in[0];
  const float* W_fc_in = (const float*)d_in[1];
  const float* b_fc_in = (const float*)d_in[2];
  const float* W_ih    = (const float*)d_in[3];
  const float* W_hh    = (const float*)d_in[4];
  const float* b_ih    = (const float*)d_in[5];
  const float* b_hh    = (const float*)d_in[6];
  const float* W_out   = (const float*)d_in[7];
  const float* b_out   = (const float*)d_in[8];
  int* out = (int*)d_out;

  char* w = (char*)d_ws;
  float* h = (float*)w;          w += (size_t)BBATCH * HD * 4;        // 256 KB
  float* outs = (float*)w;       w += (size_t)NROWS * HD * 4;         // 8 MB
  ushort* outs_bf = (ushort*)w;  w += (size_t)NROWS * HD * 2;         // 4 MB
  ushort* Wbf = (ushort*)w;      w += (size_t)VOCAB * HD * 2;         // 65.5 MB
  // X region: permuted Wg splits live through the GRU; keys aliases after.
  char* X = w;                   w += (size_t)3 * GATE6 * HD * 2;     // 37.75 MB
  ushort* Wg1 = (ushort*)X;
  ushort* Wg2 = Wg1 + (size_t)GATE6 * HD;
  ushort* Wg3 = Wg2 + (size_t)GATE6 * HD;
  u64* keys = (u64*)X;                                               // alias
  ushort* h1 = (ushort*)w;       w += (size_t)BBATCH * HD * 2;        // 128 KB
  ushort* h2 = (ushort*)w;       w += (size_t)BBATCH * HD * 2;        // 128 KB
  ushort* h3 = (ushort*)w;       w += (size_t)BBATCH * HD * 2;        // 128 KB
  float* part = (float*)w;       // fc_in partials: 4*64*1024 fp32 = 1 MB

  // one-time weight conversions
  tobf16<<<4096, 256, 0, stream>>>(W_out, Wbf, VOCAB * HD / 8);
  tobf16x3_gruP<<<GATE6 * (HD / 8) / 256, 256, 0, stream>>>(W_ih, W_hh,
                                                            Wg1, Wg2, Wg3);

  // fc_in: h0 = vectors @ W_fc_in^T + b_fc_in  (fp32, split-K=4)
  gemm64_nt<<<dim3(32, 4), 256, 0, stream>>>(vectors, W_fc_in, part);
  combine_fcin<<<256, 256, 0, stream>>>(part, b_fc_in, h, h1, h2, h3);

  // 32 GRU steps, one fused GEMM+gate kernel per step (no partial exchange)
  for (int t = 0; t < TSTEP; ++t)
    gru_step<<<GBLK, 256, 0, stream>>>(Wg1, Wg2, Wg3, b_ih, b_hh,
                                       h, outs, outs_bf, h1, h2, h3, t);

  // bf16 MFMA prefilter over the vocab (2-phase pipelined)
  gemm_out_mfma<<<dim3(2, NCB), 256, 0, stream>>>(outs_bf, Wbf, b_out, keys);

  // exact fp32 rescore of top-16 + Threefry/Gumbel sampling
  merge_sample2<<<NROWS, 256, 0, stream>>>(keys, outs, W_out, b_out, out);
}

// Round 7
// 1497.547 us; speedup vs baseline: 3.2154x; 1.0217x over previous
//
#include <hip/hip_runtime.h>
#include <stdint.h>

typedef unsigned int u32;
typedef unsigned long long u64;
typedef unsigned short ushort;
typedef __attribute__((ext_vector_type(8))) short bf16x8;
typedef __attribute__((ext_vector_type(4))) float f32x4;

#define JAX_PARTITIONABLE 1

#define HD     1024
#define BBATCH 64
#define TSTEP  32
#define VOCAB  32000
#define NROWS  2048      // TSTEP * BBATCH
#define GATE6  6144      // 6 * HD
#define NCB    250       // 32000 / 128 col-blocks
#define NCAND  16

// ---------------- Threefry-2x32 (matches jax._src.prng) ----------------
__device__ __forceinline__ void threefry2x32(u32 k0, u32 k1, u32 x0, u32 x1,
                                             u32& y0, u32& y1) {
  u32 ks2 = k0 ^ k1 ^ 0x1BD11BDAu;
  x0 += k0; x1 += k1;
#define TFR(r) do { x0 += x1; x1 = (x1 << (r)) | (x1 >> (32 - (r))); x1 ^= x0; } while (0)
  TFR(13); TFR(15); TFR(26); TFR(6);   x0 += k1;  x1 += ks2 + 1u;
  TFR(17); TFR(29); TFR(16); TFR(24);  x0 += ks2; x1 += k0 + 2u;
  TFR(13); TFR(15); TFR(26); TFR(6);   x0 += k0;  x1 += k1 + 3u;
  TFR(17); TFR(29); TFR(16); TFR(24);  x0 += k1;  x1 += ks2 + 4u;
  TFR(13); TFR(15); TFR(26); TFR(6);   x0 += ks2; x1 += k0 + 5u;
#undef TFR
  y0 = x0; y1 = x1;
}

__device__ __forceinline__ u32 jax_random_bits(u32 n) {
#if JAX_PARTITIONABLE
  u32 y0, y1; threefry2x32(0u, 42u, 0u, n, y0, y1);
  return y0 ^ y1;
#else
  u32 y0, y1;
  if (n < 8192u) { threefry2x32(0u, 42u, n, n + 8192u, y0, y1); return y0; }
  else           { threefry2x32(0u, 42u, n - 8192u, n, y0, y1); return y1; }
#endif
}

// value-desc, tie -> lower vocab index wins
__device__ __forceinline__ u64 packkey(float v, int idx) {
  u32 b = __float_as_uint(v);
  b = (b & 0x80000000u) ? ~b : (b | 0x80000000u);
  return ((u64)b << 32) | (u64)(~(u32)idx);
}

__device__ __forceinline__ void insert4(u64* t4, u64 k) {
  if (k > t4[3]) {
    t4[3] = k;
    if (t4[3] > t4[2]) { u64 tm = t4[2]; t4[2] = t4[3]; t4[3] = tm; }
    if (t4[2] > t4[1]) { u64 tm = t4[1]; t4[1] = t4[2]; t4[2] = tm; }
    if (t4[1] > t4[0]) { u64 tm = t4[0]; t4[0] = t4[1]; t4[1] = tm; }
  }
}

__device__ __forceinline__ ushort f2bf_rne(float x) {
  u32 u = __float_as_uint(x);
  return (ushort)((u + 0x7fffu + ((u >> 16) & 1u)) >> 16);
}
__device__ __forceinline__ float bf2f(ushort h) {
  return __uint_as_float(((u32)h) << 16);
}

typedef const __attribute__((address_space(1))) void* gas_ptr;
typedef __attribute__((address_space(3))) void* las_ptr;
__device__ __forceinline__ void gload16(const void* g, void* l) {
  __builtin_amdgcn_global_load_lds((gas_ptr)g, (las_ptr)l, 16, 0, 0);
}

// ---------------- fp32 -> bf16 bulk convert ----------------
__global__ __launch_bounds__(256) void tobf16(const float* __restrict__ src,
                                              ushort* __restrict__ dst, int n8) {
  int i = blockIdx.x * 256 + threadIdx.x;
  const int stride = gridDim.x * 256;
  for (; i < n8; i += stride) {
    const float4* s4 = (const float4*)src + (size_t)i * 2;
    float4 a = s4[0], b = s4[1];
    u32 o0 = f2bf_rne(a.x) | ((u32)f2bf_rne(a.y) << 16);
    u32 o1 = f2bf_rne(a.z) | ((u32)f2bf_rne(a.w) << 16);
    u32 o2 = f2bf_rne(b.x) | ((u32)f2bf_rne(b.y) << 16);
    u32 o3 = f2bf_rne(b.z) | ((u32)f2bf_rne(b.w) << 16);
    ((uint4*)dst)[i] = make_uint4(o0, o1, o2, o3);
  }
}

// ------- W_ih|W_hh -> PERMUTED bf16 3-level split for block-local gates ----
// out row r' = b*48 + g*8 + j'  (b=0..127, g=0..5, j'=0..7)
__global__ __launch_bounds__(256) void tobf16x3_gruP(
    const float* __restrict__ Wih, const float* __restrict__ Whh,
    ushort* __restrict__ w1, ushort* __restrict__ w2, ushort* __restrict__ w3) {
  int i = blockIdx.x * 256 + threadIdx.x;
  if (i >= GATE6 * (HD / 8)) return;
  int rp = i >> 7;           // out row
  int kc = i & 127;          // 8-elem chunk along K
  int b = rp / 48, rem = rp % 48;
  int g = rem >> 3, jp = rem & 7;
  const float* src = (g < 3)
      ? (Wih + ((size_t)g * HD + b * 8 + jp) * HD)
      : (Whh + ((size_t)(g - 3) * HD + b * 8 + jp) * HD);
  const float4* s4 = (const float4*)(src + kc * 8);
  float v[8];
  float4 a = s4[0], bb = s4[1];
  v[0]=a.x; v[1]=a.y; v[2]=a.z; v[3]=a.w; v[4]=bb.x; v[5]=bb.y; v[6]=bb.z; v[7]=bb.w;
  ushort p1[8], p2[8], p3[8];
#pragma unroll
  for (int e = 0; e < 8; ++e) {
    p1[e] = f2bf_rne(v[e]);
    float r1 = v[e] - bf2f(p1[e]);
    p2[e] = f2bf_rne(r1);
    float r2 = r1 - bf2f(p2[e]);
    p3[e] = f2bf_rne(r2);
  }
  u32 o1[4], o2[4], o3[4];
#pragma unroll
  for (int e = 0; e < 4; ++e) {
    o1[e] = p1[2*e] | ((u32)p1[2*e+1] << 16);
    o2[e] = p2[2*e] | ((u32)p2[2*e+1] << 16);
    o3[e] = p3[2*e] | ((u32)p3[2*e+1] << 16);
  }
  ((uint4*)w1)[i] = make_uint4(o1[0], o1[1], o1[2], o1[3]);
  ((uint4*)w2)[i] = make_uint4(o2[0], o2[1], o2[2], o2[3]);
  ((uint4*)w3)[i] = make_uint4(o3[0], o3[1], o3[2], o3[3]);
}

// ---------------- fc_in skinny NT GEMM (fp32, one-time) ----------------
__global__ __launch_bounds__(256) void gemm64_nt(
    const float* __restrict__ A, const float* __restrict__ B,
    float* __restrict__ part) {
  __shared__ float4 As4[64 * 33];
  __shared__ float4 Bs4[32 * 33];
  const int tid = threadIdx.x;
  const int n0 = blockIdx.x * 32;
  const float* Brow = B + (size_t)n0 * HD;
  const int ks = blockIdx.y * 256;
  const int tc = tid & 7, trg = tid >> 3;
  float acc[2][4] = {};
  for (int kc = 0; kc < 2; ++kc) {
    const int k0 = ks + kc * 128;
#pragma unroll
    for (int l = 0; l < 8; ++l) {
      int m = tid + l * 256; int row = m >> 5, k4 = m & 31;
      As4[row * 33 + k4] = *(const float4*)(A + (size_t)row * HD + k0 + k4 * 4);
    }
#pragma unroll
    for (int l = 0; l < 4; ++l) {
      int m = tid + l * 256; int row = m >> 5, k4 = m & 31;
      Bs4[row * 33 + k4] = *(const float4*)(Brow + (size_t)row * HD + k0 + k4 * 4);
    }
    __syncthreads();
#pragma unroll
    for (int kq = 0; kq < 32; ++kq) {
      float4 av[2], bv[4];
      av[0] = As4[trg * 33 + kq];
      av[1] = As4[(trg + 32) * 33 + kq];
      bv[0] = Bs4[tc * 33 + kq];
      bv[1] = Bs4[(tc + 8) * 33 + kq];
      bv[2] = Bs4[(tc + 16) * 33 + kq];
      bv[3] = Bs4[(tc + 24) * 33 + kq];
#pragma unroll
      for (int i = 0; i < 2; ++i)
#pragma unroll
        for (int j = 0; j < 4; ++j) {
          acc[i][j] += av[i].x * bv[j].x;
          acc[i][j] += av[i].y * bv[j].y;
          acc[i][j] += av[i].z * bv[j].z;
          acc[i][j] += av[i].w * bv[j].w;
        }
    }
    __syncthreads();
  }
  float* P = part + (size_t)blockIdx.y * BBATCH * HD;
#pragma unroll
  for (int i = 0; i < 2; ++i) {
    int b = trg + 32 * i;
#pragma unroll
    for (int j = 0; j < 4; ++j)
      P[(size_t)b * HD + n0 + tc + 8 * j] = acc[i][j];
  }
}

// ---------------- fc_in combine (+ 3-level split of h0) ----------------
__global__ __launch_bounds__(256) void combine_fcin(
    const float* __restrict__ part, const float* __restrict__ b_fc,
    float* __restrict__ h, ushort* __restrict__ h1, ushort* __restrict__ h2,
    ushort* __restrict__ h3) {
  int idx = blockIdx.x * 256 + threadIdx.x;
  int j = idx & 1023; int b = idx >> 10;
  const size_t S = (size_t)BBATCH * HD;
  const float* p = part + (size_t)b * HD;
  float d = p[j]; d += p[S + j]; d += p[2 * S + j]; d += p[3 * S + j];
  float hv = d + b_fc[j];
  h[idx] = hv;
  ushort a = f2bf_rne(hv);
  float r1 = hv - bf2f(a);
  ushort bb = f2bf_rne(r1);
  float r2 = r1 - bf2f(bb);
  h1[idx] = a; h2[idx] = bb; h3[idx] = f2bf_rne(r2);
}

// ---------------- GRU one step v2: direct-A, piped LDS-B, in-reg gate ------
// 256 blocks = (jslice b 0..127) x (batch half hb 0..1); 128 thr = 2 waves,
// wave w covers batch rows hb*32 + w*16 + [0,16). K=1024 full per block.
// W' (48 rows) double-buffered in LDS with counted vmcnt(9); A (h splits)
// loaded straight to VGPR fragments (L2-resident).
__global__ __launch_bounds__(128) void gru_step(
    const ushort* __restrict__ W1, const ushort* __restrict__ W2,
    const ushort* __restrict__ W3,
    const float* __restrict__ b_ih, const float* __restrict__ b_hh,
    float* __restrict__ h, float* __restrict__ outs,
    ushort* __restrict__ outs_bf,
    ushort* __restrict__ h1, ushort* __restrict__ h2, ushort* __restrict__ h3,
    int t) {
  __shared__ ushort Bs[2][3][3072];   // [buf][level][48*64] = 36 KB
  const int tid = threadIdx.x;
  const int lane = tid & 63, w = tid >> 6;
  const int b = blockIdx.x >> 1;
  const int hb = blockIdx.x & 1;
  const ushort* B1g = W1 + (size_t)b * 48 * HD;
  const ushort* B2g = W2 + (size_t)b * 48 * HD;
  const ushort* B3g = W3 + (size_t)b * 48 * HD;
  const int rc = lane >> 3;
  const int gr8 = ((lane & 7) ^ rc) * 8;
  const int l15 = lane & 15;
  const int kc4 = lane >> 4;                 // 0..3
  const int arow = hb * 32 + w * 16 + l15;   // A-fragment row

#define STAGE_B(buf, kt) do {                                         \
    const int k0_ = (kt) * 64;                                        \
    _Pragma("unroll")                                                 \
    for (int c_ = 0; c_ < 9; ++c_) {                                  \
      int q_ = w * 9 + c_;                                            \
      const ushort* src_; ushort* dst_;                               \
      if (q_ < 6)       { src_ = B1g + (size_t)(q_ * 8 + rc) * HD;    \
                          dst_ = &Bs[buf][0][q_ * 512]; }             \
      else if (q_ < 12) { src_ = B2g + (size_t)((q_ - 6) * 8 + rc) * HD; \
                          dst_ = &Bs[buf][1][(q_ - 6) * 512]; }       \
      else              { src_ = B3g + (size_t)((q_ - 12) * 8 + rc) * HD; \
                          dst_ = &Bs[buf][2][(q_ - 12) * 512]; }      \
      gload16(src_ + k0_ + gr8, dst_);                                \
    }                                                                 \
  } while (0)

  f32x4 acc[3];
#pragma unroll
  for (int nt = 0; nt < 3; ++nt) acc[nt] = (f32x4){0.f, 0.f, 0.f, 0.f};

  STAGE_B(0, 0);
  int p = 0;
  for (int kt = 0; kt < 16; ++kt) {
    // A fragments straight from global (h splits are L2-resident)
    bf16x8 aR[2][3];
#pragma unroll
    for (int ks = 0; ks < 2; ++ks) {
      const int ke = kt * 64 + ks * 32 + kc4 * 8;
      aR[ks][0] = *(const bf16x8*)(h1 + (size_t)arow * HD + ke);
      aR[ks][1] = *(const bf16x8*)(h2 + (size_t)arow * HD + ke);
      aR[ks][2] = *(const bf16x8*)(h3 + (size_t)arow * HD + ke);
    }
    if (kt < 15) {
      STAGE_B(p ^ 1, kt + 1);
      asm volatile("s_waitcnt vmcnt(9)" ::: "memory");  // A + B(kt) done
    } else {
      asm volatile("s_waitcnt vmcnt(0)" ::: "memory");
    }
    __builtin_amdgcn_s_barrier();
    __builtin_amdgcn_sched_barrier(0);
#pragma unroll
    for (int ks = 0; ks < 2; ++ks) {
      const int kb = ks * 64 + kc4 * 16;
      bf16x8 b1[3], b2[3], b3[3];
#pragma unroll
      for (int nt = 0; nt < 3; ++nt) {
        int br = nt * 16 + l15;
        int boff = br * 128 + (kb ^ ((br & 7) << 4));
        b1[nt] = *(const bf16x8*)((const char*)&Bs[p][0][0] + boff);
        b2[nt] = *(const bf16x8*)((const char*)&Bs[p][1][0] + boff);
        b3[nt] = *(const bf16x8*)((const char*)&Bs[p][2][0] + boff);
      }
#pragma unroll
      for (int nt = 0; nt < 3; ++nt) {
        acc[nt] = __builtin_amdgcn_mfma_f32_16x16x32_bf16(aR[ks][2], b1[nt], acc[nt], 0, 0, 0);
        acc[nt] = __builtin_amdgcn_mfma_f32_16x16x32_bf16(aR[ks][0], b3[nt], acc[nt], 0, 0, 0);
        acc[nt] = __builtin_amdgcn_mfma_f32_16x16x32_bf16(aR[ks][1], b2[nt], acc[nt], 0, 0, 0);
        acc[nt] = __builtin_amdgcn_mfma_f32_16x16x32_bf16(aR[ks][1], b1[nt], acc[nt], 0, 0, 0);
        acc[nt] = __builtin_amdgcn_mfma_f32_16x16x32_bf16(aR[ks][0], b2[nt], acc[nt], 0, 0, 0);
        acc[nt] = __builtin_amdgcn_mfma_f32_16x16x32_bf16(aR[ks][0], b1[nt], acc[nt], 0, 0, 0);
      }
    }
    __builtin_amdgcn_sched_barrier(0);
    __builtin_amdgcn_s_barrier();
    p ^= 1;
  }
#undef STAGE_B

  // ---- in-register gate math (identical to R6) ----
  const bool low = (l15 < 8);
  const int j = b * 8 + l15;
  float bi_r = 0.f, bi_z = 0.f, bi_n = 0.f, bh_r = 0.f, bh_z = 0.f, bh_n = 0.f;
  if (low) {
    bi_r = b_ih[j]; bi_z = b_ih[HD + j]; bi_n = b_ih[2 * HD + j];
    bh_r = b_hh[j]; bh_z = b_hh[HD + j]; bh_n = b_hh[2 * HD + j];
  }
#pragma unroll
  for (int r = 0; r < 4; ++r) {
    float v0 = acc[0][r], v1 = acc[1][r], v2 = acc[2][r];
    float p0 = __shfl_xor(v0, 8);    // iz
    float p1 = __shfl_xor(v1, 8);    // hr
    float p2 = __shfl_xor(v2, 8);    // hn
    if (low) {
      float gir = (t == 0) ? bi_r : (v0 + bi_r);
      float giz = (t == 0) ? bi_z : (p0 + bi_z);
      float gin = (t == 0) ? bi_n : (v1 + bi_n);
      float ghr = p1 + bh_r;
      float ghz = v2 + bh_z;
      float ghn = p2 + bh_n;
      float rr = 1.0f / (1.0f + expf(-(gir + ghr)));
      float zz = 1.0f / (1.0f + expf(-(giz + ghz)));
      float nn = tanhf(gin + rr * ghn);
      int i = hb * 32 + w * 16 + (lane >> 4) * 4 + r;
      int idx = i * HD + j;
      float hp = h[idx];
      float hn2 = (1.0f - zz) * nn + zz * hp;
      h[idx] = hn2;
      size_t o = ((size_t)t * BBATCH + i) * HD + j;
      outs[o] = hn2;
      ushort a = f2bf_rne(hn2);
      outs_bf[o] = a;
      float r1 = hn2 - bf2f(a);
      ushort bb2 = f2bf_rne(r1);
      float r2 = r1 - bf2f(bb2);
      h1[idx] = a; h2[idx] = bb2; h3[idx] = f2bf_rne(r2);
    }
  }
}

// ---------------- bf16 MFMA fc_out prefilter v3 ----------------------------
// grid (250 cb, 16 rb): 128x128 tile. BK=32, 2-buffer counted-vmcnt pipeline,
// parallel 3-level top-4 epilogue (pk overlaid on idle staging LDS).
__global__ __launch_bounds__(256) void gemm_out_mfma(
    const ushort* __restrict__ Abf, const ushort* __restrict__ Bbf,
    const float* __restrict__ b_out, u64* __restrict__ keys) {
  __shared__ ushort Sm[4][4096];   // Ab0, Ab1, Bb0, Bb1 (8 KB each)
  __shared__ float Cs[32 * 133];   // 17 KB
  u64* pkL1 = (u64*)&Sm[0][0];     // 1024 u64 (epilogue overlay)
  u64* pkL2 = pkL1 + 1024;         // 256 u64

  const int tid = threadIdx.x;
  const int lane = tid & 63;
  const int wid = tid >> 6;
  const int wr = wid >> 1, wc = wid & 1;
  const int cb = blockIdx.x;
  const int n0 = cb * 128;
  const int r0 = blockIdx.y * 128;

  const ushort* Ag = Abf + (size_t)r0 * HD;
  const ushort* Bg = Bbf + (size_t)n0 * HD;
  const int rc4 = lane >> 2;
  const int gs8 = ((lane & 3) ^ ((lane >> 3) & 3)) * 8;
  const int l15 = lane & 15;
  const int swoff = (((lane >> 4) ^ ((l15 >> 1) & 3)) << 4);

#define STAGE_OUT(AB, BB, k0) do {                                   \
    _Pragma("unroll")                                                \
    for (int c_ = 0; c_ < 2; ++c_) {                                 \
      int ch_ = wid * 2 + c_;                                        \
      int row_ = ch_ * 16 + rc4;                                     \
      gload16(Ag + (size_t)row_ * HD + (k0) + gs8, (AB) + ch_ * 512);\
      gload16(Bg + (size_t)row_ * HD + (k0) + gs8, (BB) + ch_ * 512);\
    }                                                                \
  } while (0)

#define COMPUTE_OUT(AB, BB) do {                                     \
    bf16x8 a_[4], b_[4];                                             \
    _Pragma("unroll")                                                \
    for (int m_ = 0; m_ < 4; ++m_)                                   \
      a_[m_] = *(const bf16x8*)((const char*)(AB) +                  \
               (wr * 64 + m_ * 16 + l15) * 64 + swoff);              \
    _Pragma("unroll")                                                \
    for (int n_ = 0; n_ < 4; ++n_)                                   \
      b_[n_] = *(const bf16x8*)((const char*)(BB) +                  \
               (wc * 64 + n_ * 16 + l15) * 64 + swoff);              \
    _Pragma("unroll")                                                \
    for (int m_ = 0; m_ < 4; ++m_)                                   \
      _Pragma("unroll")                                              \
      for (int n_ = 0; n_ < 4; ++n_)                                 \
        acc[m_][n_] = __builtin_amdgcn_mfma_f32_16x16x32_bf16(       \
            a_[m_], b_[n_], acc[m_][n_], 0, 0, 0);                   \
  } while (0)

  float bo[4];
#pragma unroll
  for (int n = 0; n < 4; ++n) bo[n] = b_out[n0 + wc * 64 + n * 16 + l15];

  f32x4 acc[4][4];
#pragma unroll
  for (int m = 0; m < 4; ++m)
#pragma unroll
    for (int n = 0; n < 4; ++n) acc[m][n] = (f32x4){0.f, 0.f, 0.f, 0.f};

  STAGE_OUT(Sm[0], Sm[2], 0);
  int p = 0;
  for (int kp = 0; kp < 32; ++kp) {
    if (kp < 31) {
      STAGE_OUT(Sm[p ^ 1], Sm[2 + (p ^ 1)], (kp + 1) * 32);
      asm volatile("s_waitcnt vmcnt(4)" ::: "memory");  // buf p done; p^1 flying
    } else {
      asm volatile("s_waitcnt vmcnt(0)" ::: "memory");
    }
    __builtin_amdgcn_s_barrier();
    __builtin_amdgcn_sched_barrier(0);
    COMPUTE_OUT(Sm[p], Sm[2 + p]);
    __builtin_amdgcn_sched_barrier(0);
    __builtin_amdgcn_s_barrier();
    p ^= 1;
  }

  // epilogue: 4 quarters of 32 rows; parallel top-4 per row over 128 cols
  for (int q = 0; q < 4; ++q) {
    if (wr == (q >> 1)) {
      int mbase = (q & 1) * 2;
#pragma unroll
      for (int mi = 0; mi < 2; ++mi) {
        int m = mbase + mi;
#pragma unroll
        for (int n = 0; n < 4; ++n) {
          int c = wc * 64 + n * 16 + l15;
#pragma unroll
          for (int j = 0; j < 4; ++j) {
            int lr = mi * 16 + (lane >> 4) * 4 + j;
            Cs[lr * 133 + c] = acc[m][n][j] + bo[n];
          }
        }
      }
    }
    __syncthreads();
    {  // level 1: 256 threads, 16 cols each
      int rr = tid >> 3, seg = tid & 7;
      const float* rp = Cs + rr * 133 + seg * 16;
      u64 t4[4] = {0, 0, 0, 0};
#pragma unroll
      for (int c = 0; c < 16; ++c) insert4(t4, packkey(rp[c], n0 + seg * 16 + c));
      u64* d = pkL1 + (rr * 8 + seg) * 4;
      d[0] = t4[0]; d[1] = t4[1]; d[2] = t4[2]; d[3] = t4[3];
    }
    __syncthreads();
    if (tid < 64) {  // level 2: merge 4 sets of 4
      int rr = tid >> 1, hf = tid & 1;
      const u64* s = pkL1 + (rr * 8 + hf * 4) * 4;
      u64 t4[4] = {s[0], s[1], s[2], s[3]};
#pragma unroll
      for (int e = 4; e < 16; ++e) insert4(t4, s[e]);
      u64* d = pkL2 + tid * 4;
      d[0] = t4[0]; d[1] = t4[1]; d[2] = t4[2]; d[3] = t4[3];
    }
    __syncthreads();
    if (tid < 32) {  // level 3: merge 2 sets, write out
      const u64* s = pkL2 + tid * 8;
      u64 t4[4] = {s[0], s[1], s[2], s[3]};
      insert4(t4, s[4]); insert4(t4, s[5]); insert4(t4, s[6]); insert4(t4, s[7]);
      int grow = r0 + q * 32 + tid;
      u64* kp2 = keys + ((size_t)grow * NCB + cb) * 4;
      kp2[0] = t4[0]; kp2[1] = t4[1]; kp2[2] = t4[2]; kp2[3] = t4[3];
    }
    __syncthreads();
  }
#undef STAGE_OUT
#undef COMPUTE_OUT
}

// ---------------- per-row: top-16 -> fp32 rescore -> top-8 -> sample ------
__global__ __launch_bounds__(256) void merge_sample2(
    const u64* __restrict__ keys, const float* __restrict__ outs,
    const float* __restrict__ W_out, const float* __restrict__ b_out,
    int* __restrict__ out) {
  const int r = blockIdx.x, tid = threadIdx.x;
  const int lane = tid & 63, wid = tid >> 6;
  __shared__ u64 K[1000];
  __shared__ u64 wmax[4];
  __shared__ u64 topw[NCAND];
  __shared__ float candv[NCAND];
  __shared__ float row_f[1024];
  for (int i = tid; i < 1000; i += 256) K[i] = keys[(size_t)r * 1000 + i];
  for (int i = tid; i < 1024; i += 256) row_f[i] = outs[(size_t)r * 1024 + i];
  __syncthreads();
  for (int it = 0; it < NCAND; ++it) {
    u64 b = 0;
#pragma unroll
    for (int l = 0; l < 4; ++l) {
      int i = tid + l * 256;
      if (i < 1000) { u64 v = K[i]; b = (v > b) ? v : b; }
    }
#pragma unroll
    for (int o = 32; o; o >>= 1) {
      u64 x = __shfl_xor(b, o);
      if (x > b) b = x;
    }
    if (lane == 0) wmax[wid] = b;
    __syncthreads();
    u64 w = wmax[0];
    if (wmax[1] > w) w = wmax[1];
    if (wmax[2] > w) w = wmax[2];
    if (wmax[3] > w) w = wmax[3];
    if (tid == 0) topw[it] = w;
#pragma unroll
    for (int l = 0; l < 4; ++l) {
      int i = tid + l * 256;
      if (i < 1000 && K[i] == w) K[i] = 0;
    }
    __syncthreads();
  }
  {
    int c = tid >> 4, l16 = tid & 15;
    int vidx = (int)(~(u32)(topw[c] & 0xffffffffu));
    const float* wrow = W_out + (size_t)vidx * HD;
    float s = 0.f;
    for (int e = l16; e < 1024; e += 16) s += row_f[e] * wrow[e];
#pragma unroll
    for (int o = 8; o; o >>= 1) s += __shfl_xor(s, o, 16);
    if (l16 == 0) candv[c] = s + b_out[vidx];
  }
  __syncthreads();
  if (tid == 0) {
    float v[NCAND]; int vi[NCAND];
#pragma unroll
    for (int q = 0; q < NCAND; ++q) {
      v[q] = candv[q];
      vi[q] = (int)(~(u32)(topw[q] & 0xffffffffu));
    }
    for (int a = 0; a < 8; ++a)
      for (int b2 = a + 1; b2 < NCAND; ++b2) {
        bool sw = (v[b2] > v[a]) || (v[b2] == v[a] && vi[b2] < vi[a]);
        if (sw) {
          float tf = v[a]; v[a] = v[b2]; v[b2] = tf;
          int ti = vi[a]; vi[a] = vi[b2]; vi[b2] = ti;
        }
      }
    const float M = v[0];
    const float TINY = 1.17549435e-38f;
    float best = -3.4e38f; int bi = 0;
    for (int k = 0; k < 8; ++k) {
      float lp = v[k] - M;
      u32 bits = jax_random_bits((u32)(r * 8 + k));
      float f = __uint_as_float((bits >> 9) | 0x3f800000u) - 1.0f;
      float u = f * (1.0f - TINY) + TINY;
      u = fmaxf(TINY, u);
      float g = -logf(-logf(u));
      float s = g + lp;
      if (s > best) { best = s; bi = k; }
    }
    int t = r >> 6, b = r & 63;
    out[b * TSTEP + t] = vi[bi];
  }
}

extern "C" void kernel_launch(void* const* d_in, const int* in_sizes, int n_in,
                              void* d_out, int out_size, void* d_ws, size_t ws_size,
                              hipStream_t stream) {
  (void)in_sizes; (void)n_in; (void)out_size; (void)ws_size;
  const float* vectors = (const float*)d_in[0];
  const float* W_fc_in = (const float*)d_in[1];
  const float* b_fc_in = (const float*)d_in[2];
  const float* W_ih    = (const float*)d_in[3];
  const float* W_hh    = (const float*)d_in[4];
  const float* b_ih    = (const float*)d_in[5];
  const float* b_hh    = (const float*)d_in[6];
  const float* W_out   = (const float*)d_in[7];
  const float* b_out   = (const float*)d_in[8];
  int* out = (int*)d_out;

  char* w = (char*)d_ws;
  float* h = (float*)w;          w += (size_t)BBATCH * HD * 4;        // 256 KB
  float* outs = (float*)w;       w += (size_t)NROWS * HD * 4;         // 8 MB
  ushort* outs_bf = (ushort*)w;  w += (size_t)NROWS * HD * 2;         // 4 MB
  ushort* Wbf = (ushort*)w;      w += (size_t)VOCAB * HD * 2;         // 65.5 MB
  // X region: permuted Wg splits live through the GRU; keys aliases after.
  char* X = w;                   w += (size_t)3 * GATE6 * HD * 2;     // 37.75 MB
  ushort* Wg1 = (ushort*)X;
  ushort* Wg2 = Wg1 + (size_t)GATE6 * HD;
  ushort* Wg3 = Wg2 + (size_t)GATE6 * HD;
  u64* keys = (u64*)X;                                               // alias
  ushort* h1 = (ushort*)w;       w += (size_t)BBATCH * HD * 2;        // 128 KB
  ushort* h2 = (ushort*)w;       w += (size_t)BBATCH * HD * 2;        // 128 KB
  ushort* h3 = (ushort*)w;       w += (size_t)BBATCH * HD * 2;        // 128 KB
  float* part = (float*)w;       // fc_in partials: 4*64*1024 fp32 = 1 MB

  // one-time weight conversions
  tobf16<<<4096, 256, 0, stream>>>(W_out, Wbf, VOCAB * HD / 8);
  tobf16x3_gruP<<<GATE6 * (HD / 8) / 256, 256, 0, stream>>>(W_ih, W_hh,
                                                            Wg1, Wg2, Wg3);

  // fc_in: h0 = vectors @ W_fc_in^T + b_fc_in  (fp32, split-K=4)
  gemm64_nt<<<dim3(32, 4), 256, 0, stream>>>(vectors, W_fc_in, part);
  combine_fcin<<<256, 256, 0, stream>>>(part, b_fc_in, h, h1, h2, h3);

  // 32 GRU steps: 256 blocks x 2 waves, direct-A + piped LDS-B
  for (int t = 0; t < TSTEP; ++t)
    gru_step<<<256, 128, 0, stream>>>(Wg1, Wg2, Wg3, b_ih, b_hh,
                                      h, outs, outs_bf, h1, h2, h3, t);

  // bf16 MFMA prefilter over the vocab (counted-vmcnt pipeline)
  gemm_out_mfma<<<dim3(NCB, 16), 256, 0, stream>>>(outs_bf, Wbf, b_out, keys);

  // exact fp32 rescore of top-16 + Threefry/Gumbel sampling
  merge_sample2<<<NROWS, 256, 0, stream>>>(keys, outs, W_out, b_out, out);
}

// Round 8
// 1165.512 us; speedup vs baseline: 4.1314x; 1.2849x over previous
//
#include <hip/hip_runtime.h>
#include <stdint.h>

typedef unsigned int u32;
typedef unsigned long long u64;
typedef unsigned short ushort;
typedef __attribute__((ext_vector_type(8))) short bf16x8;
typedef __attribute__((ext_vector_type(4))) float f32x4;

#define JAX_PARTITIONABLE 1

#define HD     1024
#define BBATCH 64
#define TSTEP  32
#define VOCAB  32000
#define NROWS  2048      // TSTEP * BBATCH
#define GATE6  6144      // 6 * HD
#define NCB    250       // 32000 / 128 col-blocks
#define NCAND  16

// ---------------- Threefry-2x32 (matches jax._src.prng) ----------------
__device__ __forceinline__ void threefry2x32(u32 k0, u32 k1, u32 x0, u32 x1,
                                             u32& y0, u32& y1) {
  u32 ks2 = k0 ^ k1 ^ 0x1BD11BDAu;
  x0 += k0; x1 += k1;
#define TFR(r) do { x0 += x1; x1 = (x1 << (r)) | (x1 >> (32 - (r))); x1 ^= x0; } while (0)
  TFR(13); TFR(15); TFR(26); TFR(6);   x0 += k1;  x1 += ks2 + 1u;
  TFR(17); TFR(29); TFR(16); TFR(24);  x0 += ks2; x1 += k0 + 2u;
  TFR(13); TFR(15); TFR(26); TFR(6);   x0 += k0;  x1 += k1 + 3u;
  TFR(17); TFR(29); TFR(16); TFR(24);  x0 += k1;  x1 += ks2 + 4u;
  TFR(13); TFR(15); TFR(26); TFR(6);   x0 += ks2; x1 += k0 + 5u;
#undef TFR
  y0 = x0; y1 = x1;
}

__device__ __forceinline__ u32 jax_random_bits(u32 n) {
#if JAX_PARTITIONABLE
  u32 y0, y1; threefry2x32(0u, 42u, 0u, n, y0, y1);
  return y0 ^ y1;
#else
  u32 y0, y1;
  if (n < 8192u) { threefry2x32(0u, 42u, n, n + 8192u, y0, y1); return y0; }
  else           { threefry2x32(0u, 42u, n - 8192u, n, y0, y1); return y1; }
#endif
}

// value-desc, tie -> lower vocab index wins
__device__ __forceinline__ u64 packkey(float v, int idx) {
  u32 b = __float_as_uint(v);
  b = (b & 0x80000000u) ? ~b : (b | 0x80000000u);
  return ((u64)b << 32) | (u64)(~(u32)idx);
}

__device__ __forceinline__ void insert4(u64* t4, u64 k) {
  if (k > t4[3]) {
    t4[3] = k;
    if (t4[3] > t4[2]) { u64 tm = t4[2]; t4[2] = t4[3]; t4[3] = tm; }
    if (t4[2] > t4[1]) { u64 tm = t4[1]; t4[1] = t4[2]; t4[2] = tm; }
    if (t4[1] > t4[0]) { u64 tm = t4[0]; t4[0] = t4[1]; t4[1] = tm; }
  }
}

__device__ __forceinline__ ushort f2bf_rne(float x) {
  u32 u = __float_as_uint(x);
  return (ushort)((u + 0x7fffu + ((u >> 16) & 1u)) >> 16);
}
__device__ __forceinline__ float bf2f(ushort h) {
  return __uint_as_float(((u32)h) << 16);
}

typedef const __attribute__((address_space(1))) void* gas_ptr;
typedef __attribute__((address_space(3))) void* las_ptr;
__device__ __forceinline__ void gload16(const void* g, void* l) {
  __builtin_amdgcn_global_load_lds((gas_ptr)g, (las_ptr)l, 16, 0, 0);
}

// ---------------- fp32 -> bf16 bulk convert ----------------
__global__ __launch_bounds__(256) void tobf16(const float* __restrict__ src,
                                              ushort* __restrict__ dst, int n8) {
  int i = blockIdx.x * 256 + threadIdx.x;
  const int stride = gridDim.x * 256;
  for (; i < n8; i += stride) {
    const float4* s4 = (const float4*)src + (size_t)i * 2;
    float4 a = s4[0], b = s4[1];
    u32 o0 = f2bf_rne(a.x) | ((u32)f2bf_rne(a.y) << 16);
    u32 o1 = f2bf_rne(a.z) | ((u32)f2bf_rne(a.w) << 16);
    u32 o2 = f2bf_rne(b.x) | ((u32)f2bf_rne(b.y) << 16);
    u32 o3 = f2bf_rne(b.z) | ((u32)f2bf_rne(b.w) << 16);
    ((uint4*)dst)[i] = make_uint4(o0, o1, o2, o3);
  }
}

// ------- W_ih|W_hh -> PERMUTED bf16 3-level split for block-local gates ----
// out row r' = b*48 + g*8 + j'  (b=0..127, g=0..5, j'=0..7)
__global__ __launch_bounds__(256) void tobf16x3_gruP(
    const float* __restrict__ Wih, const float* __restrict__ Whh,
    ushort* __restrict__ w1, ushort* __restrict__ w2, ushort* __restrict__ w3) {
  int i = blockIdx.x * 256 + threadIdx.x;
  if (i >= GATE6 * (HD / 8)) return;
  int rp = i >> 7;           // out row
  int kc = i & 127;          // 8-elem chunk along K
  int b = rp / 48, rem = rp % 48;
  int g = rem >> 3, jp = rem & 7;
  const float* src = (g < 3)
      ? (Wih + ((size_t)g * HD + b * 8 + jp) * HD)
      : (Whh + ((size_t)(g - 3) * HD + b * 8 + jp) * HD);
  const float4* s4 = (const float4*)(src + kc * 8);
  float v[8];
  float4 a = s4[0], bb = s4[1];
  v[0]=a.x; v[1]=a.y; v[2]=a.z; v[3]=a.w; v[4]=bb.x; v[5]=bb.y; v[6]=bb.z; v[7]=bb.w;
  ushort p1[8], p2[8], p3[8];
#pragma unroll
  for (int e = 0; e < 8; ++e) {
    p1[e] = f2bf_rne(v[e]);
    float r1 = v[e] - bf2f(p1[e]);
    p2[e] = f2bf_rne(r1);
    float r2 = r1 - bf2f(p2[e]);
    p3[e] = f2bf_rne(r2);
  }
  u32 o1[4], o2[4], o3[4];
#pragma unroll
  for (int e = 0; e < 4; ++e) {
    o1[e] = p1[2*e] | ((u32)p1[2*e+1] << 16);
    o2[e] = p2[2*e] | ((u32)p2[2*e+1] << 16);
    o3[e] = p3[2*e] | ((u32)p3[2*e+1] << 16);
  }
  ((uint4*)w1)[i] = make_uint4(o1[0], o1[1], o1[2], o1[3]);
  ((uint4*)w2)[i] = make_uint4(o2[0], o2[1], o2[2], o2[3]);
  ((uint4*)w3)[i] = make_uint4(o3[0], o3[1], o3[2], o3[3]);
}

// ---------------- fc_in skinny NT GEMM (fp32, one-time) ----------------
__global__ __launch_bounds__(256) void gemm64_nt(
    const float* __restrict__ A, const float* __restrict__ B,
    float* __restrict__ part) {
  __shared__ float4 As4[64 * 33];
  __shared__ float4 Bs4[32 * 33];
  const int tid = threadIdx.x;
  const int n0 = blockIdx.x * 32;
  const float* Brow = B + (size_t)n0 * HD;
  const int ks = blockIdx.y * 256;
  const int tc = tid & 7, trg = tid >> 3;
  float acc[2][4] = {};
  for (int kc = 0; kc < 2; ++kc) {
    const int k0 = ks + kc * 128;
#pragma unroll
    for (int l = 0; l < 8; ++l) {
      int m = tid + l * 256; int row = m >> 5, k4 = m & 31;
      As4[row * 33 + k4] = *(const float4*)(A + (size_t)row * HD + k0 + k4 * 4);
    }
#pragma unroll
    for (int l = 0; l < 4; ++l) {
      int m = tid + l * 256; int row = m >> 5, k4 = m & 31;
      Bs4[row * 33 + k4] = *(const float4*)(Brow + (size_t)row * HD + k0 + k4 * 4);
    }
    __syncthreads();
#pragma unroll
    for (int kq = 0; kq < 32; ++kq) {
      float4 av[2], bv[4];
      av[0] = As4[trg * 33 + kq];
      av[1] = As4[(trg + 32) * 33 + kq];
      bv[0] = Bs4[tc * 33 + kq];
      bv[1] = Bs4[(tc + 8) * 33 + kq];
      bv[2] = Bs4[(tc + 16) * 33 + kq];
      bv[3] = Bs4[(tc + 24) * 33 + kq];
#pragma unroll
      for (int i = 0; i < 2; ++i)
#pragma unroll
        for (int j = 0; j < 4; ++j) {
          acc[i][j] += av[i].x * bv[j].x;
          acc[i][j] += av[i].y * bv[j].y;
          acc[i][j] += av[i].z * bv[j].z;
          acc[i][j] += av[i].w * bv[j].w;
        }
    }
    __syncthreads();
  }
  float* P = part + (size_t)blockIdx.y * BBATCH * HD;
#pragma unroll
  for (int i = 0; i < 2; ++i) {
    int b = trg + 32 * i;
#pragma unroll
    for (int j = 0; j < 4; ++j)
      P[(size_t)b * HD + n0 + tc + 8 * j] = acc[i][j];
  }
}

// ---------------- fc_in combine (+ 3-level split of h0) ----------------
__global__ __launch_bounds__(256) void combine_fcin(
    const float* __restrict__ part, const float* __restrict__ b_fc,
    float* __restrict__ h, ushort* __restrict__ h1, ushort* __restrict__ h2,
    ushort* __restrict__ h3) {
  int idx = blockIdx.x * 256 + threadIdx.x;
  int j = idx & 1023; int b = idx >> 10;
  const size_t S = (size_t)BBATCH * HD;
  const float* p = part + (size_t)b * HD;
  float d = p[j]; d += p[S + j]; d += p[2 * S + j]; d += p[3 * S + j];
  float hv = d + b_fc[j];
  h[idx] = hv;
  ushort a = f2bf_rne(hv);
  float r1 = hv - bf2f(a);
  ushort bb = f2bf_rne(r1);
  float r2 = r1 - bf2f(bb);
  h1[idx] = a; h2[idx] = bb; h3[idx] = f2bf_rne(r2);
}

// ---------------- GRU one step v3: 2-deep pipeline, in-reg gate -------------
// 256 blocks = (jslice b 0..127) x (batch half hb 0..1); 128 thr = 2 waves.
// A (h splits) prefetched to VGPR one iter ahead; W' double-buffered in LDS;
// steady-state wait = vmcnt(15) (next iter's 6 A + 9 B stay in flight).
__global__ __launch_bounds__(128) void gru_step(
    const ushort* __restrict__ W1, const ushort* __restrict__ W2,
    const ushort* __restrict__ W3,
    const float* __restrict__ b_ih, const float* __restrict__ b_hh,
    float* __restrict__ h, float* __restrict__ outs,
    ushort* __restrict__ outs_bf,
    ushort* __restrict__ h1, ushort* __restrict__ h2, ushort* __restrict__ h3,
    int t) {
  __shared__ ushort Bs[2][3][3072];   // [buf][level][48*64] = 36 KB
  const int tid = threadIdx.x;
  const int lane = tid & 63, w = tid >> 6;
  const int b = blockIdx.x >> 1;
  const int hb = blockIdx.x & 1;
  const ushort* B1g = W1 + (size_t)b * 48 * HD;
  const ushort* B2g = W2 + (size_t)b * 48 * HD;
  const ushort* B3g = W3 + (size_t)b * 48 * HD;
  const int rc = lane >> 3;
  const int gr8 = ((lane & 7) ^ rc) * 8;
  const int l15 = lane & 15;
  const int kc4 = lane >> 4;                 // 0..3
  const int arow = hb * 32 + w * 16 + l15;   // A-fragment row

#define STAGE_B(buf, kt) do {                                         \
    const int k0_ = (kt) * 64;                                        \
    _Pragma("unroll")                                                 \
    for (int c_ = 0; c_ < 9; ++c_) {                                  \
      int q_ = w * 9 + c_;                                            \
      const ushort* src_; ushort* dst_;                               \
      if (q_ < 6)       { src_ = B1g + (size_t)(q_ * 8 + rc) * HD;    \
                          dst_ = &Bs[buf][0][q_ * 512]; }             \
      else if (q_ < 12) { src_ = B2g + (size_t)((q_ - 6) * 8 + rc) * HD; \
                          dst_ = &Bs[buf][1][(q_ - 6) * 512]; }       \
      else              { src_ = B3g + (size_t)((q_ - 12) * 8 + rc) * HD; \
                          dst_ = &Bs[buf][2][(q_ - 12) * 512]; }      \
      gload16(src_ + k0_ + gr8, dst_);                                \
    }                                                                 \
  } while (0)

#define LOAD_A(dst, kt) do {                                          \
    _Pragma("unroll")                                                 \
    for (int ks_ = 0; ks_ < 2; ++ks_) {                               \
      const int ke_ = (kt) * 64 + ks_ * 32 + kc4 * 8;                 \
      dst[ks_][0] = *(const bf16x8*)(h1 + (size_t)arow * HD + ke_);   \
      dst[ks_][1] = *(const bf16x8*)(h2 + (size_t)arow * HD + ke_);   \
      dst[ks_][2] = *(const bf16x8*)(h3 + (size_t)arow * HD + ke_);   \
    }                                                                 \
  } while (0)

#define COMPUTE_G(AR, buf) do {                                       \
    _Pragma("unroll")                                                 \
    for (int ks_ = 0; ks_ < 2; ++ks_) {                               \
      const int kb_ = ks_ * 64 + kc4 * 16;                            \
      bf16x8 b1_[3], b2_[3], b3_[3];                                  \
      _Pragma("unroll")                                               \
      for (int nt_ = 0; nt_ < 3; ++nt_) {                             \
        int br_ = nt_ * 16 + l15;                                     \
        int bo_ = br_ * 128 + (kb_ ^ ((br_ & 7) << 4));               \
        b1_[nt_] = *(const bf16x8*)((const char*)&Bs[buf][0][0] + bo_); \
        b2_[nt_] = *(const bf16x8*)((const char*)&Bs[buf][1][0] + bo_); \
        b3_[nt_] = *(const bf16x8*)((const char*)&Bs[buf][2][0] + bo_); \
      }                                                               \
      _Pragma("unroll")                                               \
      for (int nt_ = 0; nt_ < 3; ++nt_) {                             \
        acc[nt_] = __builtin_amdgcn_mfma_f32_16x16x32_bf16(AR[ks_][2], b1_[nt_], acc[nt_], 0, 0, 0); \
        acc[nt_] = __builtin_amdgcn_mfma_f32_16x16x32_bf16(AR[ks_][0], b3_[nt_], acc[nt_], 0, 0, 0); \
        acc[nt_] = __builtin_amdgcn_mfma_f32_16x16x32_bf16(AR[ks_][1], b2_[nt_], acc[nt_], 0, 0, 0); \
        acc[nt_] = __builtin_amdgcn_mfma_f32_16x16x32_bf16(AR[ks_][1], b1_[nt_], acc[nt_], 0, 0, 0); \
        acc[nt_] = __builtin_amdgcn_mfma_f32_16x16x32_bf16(AR[ks_][0], b2_[nt_], acc[nt_], 0, 0, 0); \
        acc[nt_] = __builtin_amdgcn_mfma_f32_16x16x32_bf16(AR[ks_][0], b1_[nt_], acc[nt_], 0, 0, 0); \
      }                                                               \
    }                                                                 \
  } while (0)

  f32x4 acc[3];
#pragma unroll
  for (int nt = 0; nt < 3; ++nt) acc[nt] = (f32x4){0.f, 0.f, 0.f, 0.f};

  bf16x8 aA[2][3], aB[2][3];
  LOAD_A(aA, 0); STAGE_B(0, 0);
  LOAD_A(aB, 1); STAGE_B(1, 1);

#pragma unroll
  for (int kt2 = 0; kt2 < 8; ++kt2) {
    const int kte = kt2 * 2, kto = kte + 1;
    // even step: uses aA, Bs[0]
    asm volatile("s_waitcnt vmcnt(15)" ::: "memory");
    __builtin_amdgcn_s_barrier();
    __builtin_amdgcn_sched_barrier(0);
    COMPUTE_G(aA, 0);
    __builtin_amdgcn_sched_barrier(0);
    __builtin_amdgcn_s_barrier();
    if (kte + 2 < 16) { LOAD_A(aA, kte + 2); STAGE_B(0, kte + 2); }
    // odd step: uses aB, Bs[1]
    if (kto < 15) {
      asm volatile("s_waitcnt vmcnt(15)" ::: "memory");
    } else {
      asm volatile("s_waitcnt vmcnt(0)" ::: "memory");
    }
    __builtin_amdgcn_s_barrier();
    __builtin_amdgcn_sched_barrier(0);
    COMPUTE_G(aB, 1);
    __builtin_amdgcn_sched_barrier(0);
    __builtin_amdgcn_s_barrier();
    if (kto + 2 < 16) { LOAD_A(aB, kto + 2); STAGE_B(1, kto + 2); }
  }
#undef STAGE_B
#undef LOAD_A
#undef COMPUTE_G

  // ---- in-register gate math (identical to R7) ----
  const bool low = (l15 < 8);
  const int j = b * 8 + l15;
  float bi_r = 0.f, bi_z = 0.f, bi_n = 0.f, bh_r = 0.f, bh_z = 0.f, bh_n = 0.f;
  if (low) {
    bi_r = b_ih[j]; bi_z = b_ih[HD + j]; bi_n = b_ih[2 * HD + j];
    bh_r = b_hh[j]; bh_z = b_hh[HD + j]; bh_n = b_hh[2 * HD + j];
  }
#pragma unroll
  for (int r = 0; r < 4; ++r) {
    float v0 = acc[0][r], v1 = acc[1][r], v2 = acc[2][r];
    float p0 = __shfl_xor(v0, 8);    // iz
    float p1 = __shfl_xor(v1, 8);    // hr
    float p2 = __shfl_xor(v2, 8);    // hn
    if (low) {
      float gir = (t == 0) ? bi_r : (v0 + bi_r);
      float giz = (t == 0) ? bi_z : (p0 + bi_z);
      float gin = (t == 0) ? bi_n : (v1 + bi_n);
      float ghr = p1 + bh_r;
      float ghz = v2 + bh_z;
      float ghn = p2 + bh_n;
      float rr = 1.0f / (1.0f + expf(-(gir + ghr)));
      float zz = 1.0f / (1.0f + expf(-(giz + ghz)));
      float nn = tanhf(gin + rr * ghn);
      int i = hb * 32 + w * 16 + (lane >> 4) * 4 + r;
      int idx = i * HD + j;
      float hp = h[idx];
      float hn2 = (1.0f - zz) * nn + zz * hp;
      h[idx] = hn2;
      size_t o = ((size_t)t * BBATCH + i) * HD + j;
      outs[o] = hn2;
      ushort a = f2bf_rne(hn2);
      outs_bf[o] = a;
      float r1 = hn2 - bf2f(a);
      ushort bb2 = f2bf_rne(r1);
      float r2 = r1 - bf2f(bb2);
      h1[idx] = a; h2[idx] = bb2; h3[idx] = f2bf_rne(r2);
    }
  }
}

// ---------------- bf16 MFMA fc_out prefilter v4 ----------------------------
// grid (16 rb, 250 cb): xcd = rb%8 -> A-tiles pinned per XCD, W slices read
// once per XCD. BK=32 counted-vmcnt pipeline; fully-unrolled epilogue (no
// runtime acc indexing -> no scratch spill).
__global__ __launch_bounds__(256) void gemm_out_mfma(
    const ushort* __restrict__ Abf, const ushort* __restrict__ Bbf,
    const float* __restrict__ b_out, u64* __restrict__ keys) {
  __shared__ ushort Sm[4][4096];   // Ab0, Ab1, Bb0, Bb1 (8 KB each)
  __shared__ float Cs[32 * 133];   // 17 KB
  u64* pkL1 = (u64*)&Sm[0][0];     // 1024 u64 (epilogue overlay)
  u64* pkL2 = pkL1 + 1024;         // 256 u64

  const int tid = threadIdx.x;
  const int lane = tid & 63;
  const int wid = tid >> 6;
  const int wr = wid >> 1, wc = wid & 1;
  const int cb = blockIdx.y;
  const int n0 = cb * 128;
  const int r0 = blockIdx.x * 128;

  const ushort* Ag = Abf + (size_t)r0 * HD;
  const ushort* Bg = Bbf + (size_t)n0 * HD;
  const int rc4 = lane >> 2;
  const int gs8 = ((lane & 3) ^ ((lane >> 3) & 3)) * 8;
  const int l15 = lane & 15;
  const int swoff = (((lane >> 4) ^ ((l15 >> 1) & 3)) << 4);

#define STAGE_OUT(AB, BB, k0) do {                                   \
    _Pragma("unroll")                                                \
    for (int c_ = 0; c_ < 2; ++c_) {                                 \
      int ch_ = wid * 2 + c_;                                        \
      int row_ = ch_ * 16 + rc4;                                     \
      gload16(Ag + (size_t)row_ * HD + (k0) + gs8, (AB) + ch_ * 512);\
      gload16(Bg + (size_t)row_ * HD + (k0) + gs8, (BB) + ch_ * 512);\
    }                                                                \
  } while (0)

#define COMPUTE_OUT(AB, BB) do {                                     \
    bf16x8 a_[4], b_[4];                                             \
    _Pragma("unroll")                                                \
    for (int m_ = 0; m_ < 4; ++m_)                                   \
      a_[m_] = *(const bf16x8*)((const char*)(AB) +                  \
               (wr * 64 + m_ * 16 + l15) * 64 + swoff);              \
    _Pragma("unroll")                                                \
    for (int n_ = 0; n_ < 4; ++n_)                                   \
      b_[n_] = *(const bf16x8*)((const char*)(BB) +                  \
               (wc * 64 + n_ * 16 + l15) * 64 + swoff);              \
    _Pragma("unroll")                                                \
    for (int m_ = 0; m_ < 4; ++m_)                                   \
      _Pragma("unroll")                                              \
      for (int n_ = 0; n_ < 4; ++n_)                                 \
        acc[m_][n_] = __builtin_amdgcn_mfma_f32_16x16x32_bf16(       \
            a_[m_], b_[n_], acc[m_][n_], 0, 0, 0);                   \
  } while (0)

  float bo[4];
#pragma unroll
  for (int n = 0; n < 4; ++n) bo[n] = b_out[n0 + wc * 64 + n * 16 + l15];

  f32x4 acc[4][4];
#pragma unroll
  for (int m = 0; m < 4; ++m)
#pragma unroll
    for (int n = 0; n < 4; ++n) acc[m][n] = (f32x4){0.f, 0.f, 0.f, 0.f};

  STAGE_OUT(Sm[0], Sm[2], 0);
  int p = 0;
  for (int kp = 0; kp < 32; ++kp) {
    if (kp < 31) {
      STAGE_OUT(Sm[p ^ 1], Sm[2 + (p ^ 1)], (kp + 1) * 32);
      asm volatile("s_waitcnt vmcnt(4)" ::: "memory");  // buf p done; p^1 flying
    } else {
      asm volatile("s_waitcnt vmcnt(0)" ::: "memory");
    }
    __builtin_amdgcn_s_barrier();
    __builtin_amdgcn_sched_barrier(0);
    COMPUTE_OUT(Sm[p], Sm[2 + p]);
    __builtin_amdgcn_sched_barrier(0);
    __builtin_amdgcn_s_barrier();
    p ^= 1;
  }

  // epilogue: fully unrolled q (static acc indices -> stays in registers)
#pragma unroll
  for (int q = 0; q < 4; ++q) {
    if (wr == (q >> 1)) {
#pragma unroll
      for (int mi = 0; mi < 2; ++mi) {
        const int m = (q & 1) * 2 + mi;
#pragma unroll
        for (int n = 0; n < 4; ++n) {
          int c = wc * 64 + n * 16 + l15;
#pragma unroll
          for (int j = 0; j < 4; ++j) {
            int lr = mi * 16 + (lane >> 4) * 4 + j;
            Cs[lr * 133 + c] = acc[m][n][j] + bo[n];
          }
        }
      }
    }
    __syncthreads();
    {  // level 1: 256 threads, 16 cols each
      int rr = tid >> 3, seg = tid & 7;
      const float* rp = Cs + rr * 133 + seg * 16;
      u64 t4[4] = {0, 0, 0, 0};
#pragma unroll
      for (int c = 0; c < 16; ++c) insert4(t4, packkey(rp[c], n0 + seg * 16 + c));
      u64* d = pkL1 + (rr * 8 + seg) * 4;
      d[0] = t4[0]; d[1] = t4[1]; d[2] = t4[2]; d[3] = t4[3];
    }
    __syncthreads();
    if (tid < 64) {  // level 2: merge 4 sets of 4
      int rr = tid >> 1, hf = tid & 1;
      const u64* s = pkL1 + (rr * 8 + hf * 4) * 4;
      u64 t4[4] = {s[0], s[1], s[2], s[3]};
#pragma unroll
      for (int e = 4; e < 16; ++e) insert4(t4, s[e]);
      u64* d = pkL2 + tid * 4;
      d[0] = t4[0]; d[1] = t4[1]; d[2] = t4[2]; d[3] = t4[3];
    }
    __syncthreads();
    if (tid < 32) {  // level 3: merge 2 sets, write out
      const u64* s = pkL2 + tid * 8;
      u64 t4[4] = {s[0], s[1], s[2], s[3]};
      insert4(t4, s[4]); insert4(t4, s[5]); insert4(t4, s[6]); insert4(t4, s[7]);
      int grow = r0 + q * 32 + tid;
      u64* kp2 = keys + ((size_t)grow * NCB + cb) * 4;
      kp2[0] = t4[0]; kp2[1] = t4[1]; kp2[2] = t4[2]; kp2[3] = t4[3];
    }
    __syncthreads();
  }
#undef STAGE_OUT
#undef COMPUTE_OUT
}

// ---------------- per-row merge v2: 1 wave, reg-resident, no barriers ------
// per-lane top-8 of its ~16 strided keys (P[true top-16 not covered] ~1e-7),
// 16 wave-synchronous argmax-kill rounds, 4-lane float4 rescore, lane-0 tail.
__global__ __launch_bounds__(64) void merge_sample2(
    const u64* __restrict__ keys, const float* __restrict__ outs,
    const float* __restrict__ W_out, const float* __restrict__ b_out,
    int* __restrict__ out) {
  const int r = blockIdx.x;
  const int lane = threadIdx.x;
  __shared__ float row_f[1024];
  {
    const float4* src = (const float4*)(outs + (size_t)r * HD);
    float4* dst = (float4*)row_f;
#pragma unroll
    for (int m = 0; m < 4; ++m) dst[lane + m * 64] = src[lane + m * 64];
  }
  // per-lane sorted top-8
  u64 t8[8] = {0, 0, 0, 0, 0, 0, 0, 0};
  const u64* KR = keys + (size_t)r * 1000;
#pragma unroll
  for (int m = 0; m < 16; ++m) {
    int i = lane + (m << 6);
    if (i < 1000) {
      u64 k = KR[i];
      if (k > t8[7]) {
        t8[7] = k;
#pragma unroll
        for (int e = 7; e > 0; --e) {
          u64 hi = t8[e - 1], lo = t8[e];
          t8[e - 1] = (lo > hi) ? lo : hi;
          t8[e]     = (lo > hi) ? hi : lo;
        }
      }
    }
  }
  // 16 argmax-kill rounds (wave-synchronous, registers only)
  const int mycand = lane >> 2;
  u64 myw = 0;
#pragma unroll
  for (int it = 0; it < NCAND; ++it) {
    u64 bmax = t8[0];
#pragma unroll
    for (int o = 32; o; o >>= 1) {
      u64 x = __shfl_xor(bmax, o);
      if (x > bmax) bmax = x;
    }
    if (it == mycand) myw = bmax;
    if (t8[0] == bmax) {
#pragma unroll
      for (int e = 0; e < 7; ++e) t8[e] = t8[e + 1];
      t8[7] = 0;
    }
  }
  // exact fp32 rescore: candidate c = lane>>2, 4 lanes interleave float4
  const int myvi = (int)(~(u32)(myw & 0xffffffffu));
  float mysum;
  {
    const float4* wrow = (const float4*)(W_out + (size_t)myvi * HD);
    const float4* rf = (const float4*)row_f;
    const int q = lane & 3;
    float s = 0.f;
#pragma unroll
    for (int m2 = 0; m2 < 64; ++m2) {
      float4 a = rf[q + m2 * 4];
      float4 bb = wrow[q + m2 * 4];
      s += a.x * bb.x; s += a.y * bb.y; s += a.z * bb.z; s += a.w * bb.w;
    }
    s += __shfl_xor(s, 1);
    s += __shfl_xor(s, 2);
    mysum = s + b_out[myvi];
  }
  // gather all 16 (value, idx) to every lane via shfl; lane 0 finishes
  float v[NCAND]; int vi[NCAND];
#pragma unroll
  for (int c = 0; c < NCAND; ++c) {
    v[c] = __shfl(mysum, c * 4);
    vi[c] = __shfl(myvi, c * 4);
  }
  if (lane == 0) {
#pragma unroll
    for (int a = 0; a < 8; ++a)
#pragma unroll
      for (int b2 = a + 1; b2 < NCAND; ++b2) {
        bool sw = (v[b2] > v[a]) || (v[b2] == v[a] && vi[b2] < vi[a]);
        if (sw) {
          float tf = v[a]; v[a] = v[b2]; v[b2] = tf;
          int ti = vi[a]; vi[a] = vi[b2]; vi[b2] = ti;
        }
      }
    const float M = v[0];
    const float TINY = 1.17549435e-38f;
    float best = -3.4e38f; int bi = 0;
#pragma unroll
    for (int k = 0; k < 8; ++k) {
      float lp = v[k] - M;
      u32 bits = jax_random_bits((u32)(r * 8 + k));
      float f = __uint_as_float((bits >> 9) | 0x3f800000u) - 1.0f;
      float u = f * (1.0f - TINY) + TINY;
      u = fmaxf(TINY, u);
      float g = -logf(-logf(u));
      float s = g + lp;
      if (s > best) { best = s; bi = k; }
    }
    int t = r >> 6, b = r & 63;
    out[b * TSTEP + t] = vi[bi];
  }
}

extern "C" void kernel_launch(void* const* d_in, const int* in_sizes, int n_in,
                              void* d_out, int out_size, void* d_ws, size_t ws_size,
                              hipStream_t stream) {
  (void)in_sizes; (void)n_in; (void)out_size; (void)ws_size;
  const float* vectors = (const float*)d_in[0];
  const float* W_fc_in = (const float*)d_in[1];
  const float* b_fc_in = (const float*)d_in[2];
  const float* W_ih    = (const float*)d_in[3];
  const float* W_hh    = (const float*)d_in[4];
  const float* b_ih    = (const float*)d_in[5];
  const float* b_hh    = (const float*)d_in[6];
  const float* W_out   = (const float*)d_in[7];
  const float* b_out   = (const float*)d_in[8];
  int* out = (int*)d_out;

  char* w = (char*)d_ws;
  float* h = (float*)w;          w += (size_t)BBATCH * HD * 4;        // 256 KB
  float* outs = (float*)w;       w += (size_t)NROWS * HD * 4;         // 8 MB
  ushort* outs_bf = (ushort*)w;  w += (size_t)NROWS * HD * 2;         // 4 MB
  ushort* Wbf = (ushort*)w;      w += (size_t)VOCAB * HD * 2;         // 65.5 MB
  // X region: permuted Wg splits live through the GRU; keys aliases after.
  char* X = w;                   w += (size_t)3 * GATE6 * HD * 2;     // 37.75 MB
  ushort* Wg1 = (ushort*)X;
  ushort* Wg2 = Wg1 + (size_t)GATE6 * HD;
  ushort* Wg3 = Wg2 + (size_t)GATE6 * HD;
  u64* keys = (u64*)X;                                               // alias
  ushort* h1 = (ushort*)w;       w += (size_t)BBATCH * HD * 2;        // 128 KB
  ushort* h2 = (ushort*)w;       w += (size_t)BBATCH * HD * 2;        // 128 KB
  ushort* h3 = (ushort*)w;       w += (size_t)BBATCH * HD * 2;        // 128 KB
  float* part = (float*)w;       // fc_in partials: 4*64*1024 fp32 = 1 MB

  // one-time weight conversions
  tobf16<<<4096, 256, 0, stream>>>(W_out, Wbf, VOCAB * HD / 8);
  tobf16x3_gruP<<<GATE6 * (HD / 8) / 256, 256, 0, stream>>>(W_ih, W_hh,
                                                            Wg1, Wg2, Wg3);

  // fc_in: h0 = vectors @ W_fc_in^T + b_fc_in  (fp32, split-K=4)
  gemm64_nt<<<dim3(32, 4), 256, 0, stream>>>(vectors, W_fc_in, part);
  combine_fcin<<<256, 256, 0, stream>>>(part, b_fc_in, h, h1, h2, h3);

  // 32 GRU steps: 256 blocks x 2 waves, 2-deep prefetch pipeline
  for (int t = 0; t < TSTEP; ++t)
    gru_step<<<256, 128, 0, stream>>>(Wg1, Wg2, Wg3, b_ih, b_hh,
                                      h, outs, outs_bf, h1, h2, h3, t);

  // bf16 MFMA prefilter over the vocab (XCD-pinned A-tiles)
  gemm_out_mfma<<<dim3(16, NCB), 256, 0, stream>>>(outs_bf, Wbf, b_out, keys);

  // per-row top-16 select + exact fp32 rescore + Threefry/Gumbel sampling
  merge_sample2<<<NROWS, 64, 0, stream>>>(keys, outs, W_out, b_out, out);
}

// Round 9
// 1070.114 us; speedup vs baseline: 4.4997x; 1.0891x over previous
//
#include <hip/hip_runtime.h>
#include <stdint.h>

typedef unsigned int u32;
typedef unsigned long long u64;
typedef unsigned short ushort;
typedef __attribute__((ext_vector_type(8))) short bf16x8;
typedef __attribute__((ext_vector_type(4))) float f32x4;

#define JAX_PARTITIONABLE 1

#define HD     1024
#define BBATCH 64
#define TSTEP  32
#define VOCAB  32000
#define NROWS  2048      // TSTEP * BBATCH
#define GATE6  6144      // 6 * HD
#define NCB    250       // 32000 / 128 col-blocks
#define NCAND  16

// ---------------- Threefry-2x32 (matches jax._src.prng) ----------------
__device__ __forceinline__ void threefry2x32(u32 k0, u32 k1, u32 x0, u32 x1,
                                             u32& y0, u32& y1) {
  u32 ks2 = k0 ^ k1 ^ 0x1BD11BDAu;
  x0 += k0; x1 += k1;
#define TFR(r) do { x0 += x1; x1 = (x1 << (r)) | (x1 >> (32 - (r))); x1 ^= x0; } while (0)
  TFR(13); TFR(15); TFR(26); TFR(6);   x0 += k1;  x1 += ks2 + 1u;
  TFR(17); TFR(29); TFR(16); TFR(24);  x0 += ks2; x1 += k0 + 2u;
  TFR(13); TFR(15); TFR(26); TFR(6);   x0 += k0;  x1 += k1 + 3u;
  TFR(17); TFR(29); TFR(16); TFR(24);  x0 += k1;  x1 += ks2 + 4u;
  TFR(13); TFR(15); TFR(26); TFR(6);   x0 += ks2; x1 += k0 + 5u;
#undef TFR
  y0 = x0; y1 = x1;
}

__device__ __forceinline__ u32 jax_random_bits(u32 n) {
#if JAX_PARTITIONABLE
  u32 y0, y1; threefry2x32(0u, 42u, 0u, n, y0, y1);
  return y0 ^ y1;
#else
  u32 y0, y1;
  if (n < 8192u) { threefry2x32(0u, 42u, n, n + 8192u, y0, y1); return y0; }
  else           { threefry2x32(0u, 42u, n - 8192u, n, y0, y1); return y1; }
#endif
}

// value-desc, tie -> lower vocab index wins
__device__ __forceinline__ u64 packkey(float v, int idx) {
  u32 b = __float_as_uint(v);
  b = (b & 0x80000000u) ? ~b : (b | 0x80000000u);
  return ((u64)b << 32) | (u64)(~(u32)idx);
}

__device__ __forceinline__ void insert4(u64* t4, u64 k) {
  if (k > t4[3]) {
    t4[3] = k;
    if (t4[3] > t4[2]) { u64 tm = t4[2]; t4[2] = t4[3]; t4[3] = tm; }
    if (t4[2] > t4[1]) { u64 tm = t4[1]; t4[1] = t4[2]; t4[2] = tm; }
    if (t4[1] > t4[0]) { u64 tm = t4[0]; t4[0] = t4[1]; t4[1] = tm; }
  }
}

__device__ __forceinline__ ushort f2bf_rne(float x) {
  u32 u = __float_as_uint(x);
  return (ushort)((u + 0x7fffu + ((u >> 16) & 1u)) >> 16);
}
__device__ __forceinline__ float bf2f(ushort h) {
  return __uint_as_float(((u32)h) << 16);
}

typedef const __attribute__((address_space(1))) void* gas_ptr;
typedef __attribute__((address_space(3))) void* las_ptr;
__device__ __forceinline__ void gload16(const void* g, void* l) {
  __builtin_amdgcn_global_load_lds((gas_ptr)g, (las_ptr)l, 16, 0, 0);
}

// ---------------- fp32 -> bf16 bulk convert ----------------
__global__ __launch_bounds__(256) void tobf16(const float* __restrict__ src,
                                              ushort* __restrict__ dst, int n8) {
  int i = blockIdx.x * 256 + threadIdx.x;
  const int stride = gridDim.x * 256;
  for (; i < n8; i += stride) {
    const float4* s4 = (const float4*)src + (size_t)i * 2;
    float4 a = s4[0], b = s4[1];
    u32 o0 = f2bf_rne(a.x) | ((u32)f2bf_rne(a.y) << 16);
    u32 o1 = f2bf_rne(a.z) | ((u32)f2bf_rne(a.w) << 16);
    u32 o2 = f2bf_rne(b.x) | ((u32)f2bf_rne(b.y) << 16);
    u32 o3 = f2bf_rne(b.z) | ((u32)f2bf_rne(b.w) << 16);
    ((uint4*)dst)[i] = make_uint4(o0, o1, o2, o3);
  }
}

// ------- W_ih|W_hh -> PERMUTED bf16 3-level split for block-local gates ----
// out row r' = b*48 + g*8 + j'  (b=0..127, g=0..5, j'=0..7)
__global__ __launch_bounds__(256) void tobf16x3_gruP(
    const float* __restrict__ Wih, const float* __restrict__ Whh,
    ushort* __restrict__ w1, ushort* __restrict__ w2, ushort* __restrict__ w3) {
  int i = blockIdx.x * 256 + threadIdx.x;
  if (i >= GATE6 * (HD / 8)) return;
  int rp = i >> 7;           // out row
  int kc = i & 127;          // 8-elem chunk along K
  int b = rp / 48, rem = rp % 48;
  int g = rem >> 3, jp = rem & 7;
  const float* src = (g < 3)
      ? (Wih + ((size_t)g * HD + b * 8 + jp) * HD)
      : (Whh + ((size_t)(g - 3) * HD + b * 8 + jp) * HD);
  const float4* s4 = (const float4*)(src + kc * 8);
  float v[8];
  float4 a = s4[0], bb = s4[1];
  v[0]=a.x; v[1]=a.y; v[2]=a.z; v[3]=a.w; v[4]=bb.x; v[5]=bb.y; v[6]=bb.z; v[7]=bb.w;
  ushort p1[8], p2[8], p3[8];
#pragma unroll
  for (int e = 0; e < 8; ++e) {
    p1[e] = f2bf_rne(v[e]);
    float r1 = v[e] - bf2f(p1[e]);
    p2[e] = f2bf_rne(r1);
    float r2 = r1 - bf2f(p2[e]);
    p3[e] = f2bf_rne(r2);
  }
  u32 o1[4], o2[4], o3[4];
#pragma unroll
  for (int e = 0; e < 4; ++e) {
    o1[e] = p1[2*e] | ((u32)p1[2*e+1] << 16);
    o2[e] = p2[2*e] | ((u32)p2[2*e+1] << 16);
    o3[e] = p3[2*e] | ((u32)p3[2*e+1] << 16);
  }
  ((uint4*)w1)[i] = make_uint4(o1[0], o1[1], o1[2], o1[3]);
  ((uint4*)w2)[i] = make_uint4(o2[0], o2[1], o2[2], o2[3]);
  ((uint4*)w3)[i] = make_uint4(o3[0], o3[1], o3[2], o3[3]);
}

// ---------------- fc_in skinny NT GEMM (fp32, one-time) ----------------
__global__ __launch_bounds__(256) void gemm64_nt(
    const float* __restrict__ A, const float* __restrict__ B,
    float* __restrict__ part) {
  __shared__ float4 As4[64 * 33];
  __shared__ float4 Bs4[32 * 33];
  const int tid = threadIdx.x;
  const int n0 = blockIdx.x * 32;
  const float* Brow = B + (size_t)n0 * HD;
  const int ks = blockIdx.y * 256;
  const int tc = tid & 7, trg = tid >> 3;
  float acc[2][4] = {};
  for (int kc = 0; kc < 2; ++kc) {
    const int k0 = ks + kc * 128;
#pragma unroll
    for (int l = 0; l < 8; ++l) {
      int m = tid + l * 256; int row = m >> 5, k4 = m & 31;
      As4[row * 33 + k4] = *(const float4*)(A + (size_t)row * HD + k0 + k4 * 4);
    }
#pragma unroll
    for (int l = 0; l < 4; ++l) {
      int m = tid + l * 256; int row = m >> 5, k4 = m & 31;
      Bs4[row * 33 + k4] = *(const float4*)(Brow + (size_t)row * HD + k0 + k4 * 4);
    }
    __syncthreads();
#pragma unroll
    for (int kq = 0; kq < 32; ++kq) {
      float4 av[2], bv[4];
      av[0] = As4[trg * 33 + kq];
      av[1] = As4[(trg + 32) * 33 + kq];
      bv[0] = Bs4[tc * 33 + kq];
      bv[1] = Bs4[(tc + 8) * 33 + kq];
      bv[2] = Bs4[(tc + 16) * 33 + kq];
      bv[3] = Bs4[(tc + 24) * 33 + kq];
#pragma unroll
      for (int i = 0; i < 2; ++i)
#pragma unroll
        for (int j = 0; j < 4; ++j) {
          acc[i][j] += av[i].x * bv[j].x;
          acc[i][j] += av[i].y * bv[j].y;
          acc[i][j] += av[i].z * bv[j].z;
          acc[i][j] += av[i].w * bv[j].w;
        }
    }
    __syncthreads();
  }
  float* P = part + (size_t)blockIdx.y * BBATCH * HD;
#pragma unroll
  for (int i = 0; i < 2; ++i) {
    int b = trg + 32 * i;
#pragma unroll
    for (int j = 0; j < 4; ++j)
      P[(size_t)b * HD + n0 + tc + 8 * j] = acc[i][j];
  }
}

// ---------------- fc_in combine (+ 3-level split of h0) ----------------
__global__ __launch_bounds__(256) void combine_fcin(
    const float* __restrict__ part, const float* __restrict__ b_fc,
    float* __restrict__ h, ushort* __restrict__ h1, ushort* __restrict__ h2,
    ushort* __restrict__ h3) {
  int idx = blockIdx.x * 256 + threadIdx.x;
  int j = idx & 1023; int b = idx >> 10;
  const size_t S = (size_t)BBATCH * HD;
  const float* p = part + (size_t)b * HD;
  float d = p[j]; d += p[S + j]; d += p[2 * S + j]; d += p[3 * S + j];
  float hv = d + b_fc[j];
  h[idx] = hv;
  ushort a = f2bf_rne(hv);
  float r1 = hv - bf2f(a);
  ushort bb = f2bf_rne(r1);
  float r2 = r1 - bf2f(bb);
  h1[idx] = a; h2[idx] = bb; h3[idx] = f2bf_rne(r2);
}

// ---------------- GRU one step v4: hb-pair XCD co-location ------------------
// 256 blocks; decode so that the two batch-halves of jslice b land on the
// SAME XCD (bid = 16*(b/8) + (b%8) + 8*hb -> xcd = b%8): the pair shares its
// W' slice via that XCD's L2, halving per-step W' L3 traffic.
__global__ __launch_bounds__(128) void gru_step(
    const ushort* __restrict__ W1, const ushort* __restrict__ W2,
    const ushort* __restrict__ W3,
    const float* __restrict__ b_ih, const float* __restrict__ b_hh,
    float* __restrict__ h, float* __restrict__ outs,
    ushort* __restrict__ outs_bf,
    ushort* __restrict__ h1, ushort* __restrict__ h2, ushort* __restrict__ h3,
    int t) {
  __shared__ ushort Bs[2][3][3072];   // [buf][level][48*64] = 36 KB
  const int tid = threadIdx.x;
  const int lane = tid & 63, w = tid >> 6;
  const int grp = blockIdx.x >> 4;
  const int rmd = blockIdx.x & 15;
  const int hb = rmd >> 3;
  const int b = grp * 8 + (rmd & 7);
  const ushort* B1g = W1 + (size_t)b * 48 * HD;
  const ushort* B2g = W2 + (size_t)b * 48 * HD;
  const ushort* B3g = W3 + (size_t)b * 48 * HD;
  const int rc = lane >> 3;
  const int gr8 = ((lane & 7) ^ rc) * 8;
  const int l15 = lane & 15;
  const int kc4 = lane >> 4;                 // 0..3
  const int arow = hb * 32 + w * 16 + l15;   // A-fragment row

#define STAGE_B(buf, kt) do {                                         \
    const int k0_ = (kt) * 64;                                        \
    _Pragma("unroll")                                                 \
    for (int c_ = 0; c_ < 9; ++c_) {                                  \
      int q_ = w * 9 + c_;                                            \
      const ushort* src_; ushort* dst_;                               \
      if (q_ < 6)       { src_ = B1g + (size_t)(q_ * 8 + rc) * HD;    \
                          dst_ = &Bs[buf][0][q_ * 512]; }             \
      else if (q_ < 12) { src_ = B2g + (size_t)((q_ - 6) * 8 + rc) * HD; \
                          dst_ = &Bs[buf][1][(q_ - 6) * 512]; }       \
      else              { src_ = B3g + (size_t)((q_ - 12) * 8 + rc) * HD; \
                          dst_ = &Bs[buf][2][(q_ - 12) * 512]; }      \
      gload16(src_ + k0_ + gr8, dst_);                                \
    }                                                                 \
  } while (0)

#define LOAD_A(dst, kt) do {                                          \
    _Pragma("unroll")                                                 \
    for (int ks_ = 0; ks_ < 2; ++ks_) {                               \
      const int ke_ = (kt) * 64 + ks_ * 32 + kc4 * 8;                 \
      dst[ks_][0] = *(const bf16x8*)(h1 + (size_t)arow * HD + ke_);   \
      dst[ks_][1] = *(const bf16x8*)(h2 + (size_t)arow * HD + ke_);   \
      dst[ks_][2] = *(const bf16x8*)(h3 + (size_t)arow * HD + ke_);   \
    }                                                                 \
  } while (0)

#define COMPUTE_G(AR, buf) do {                                       \
    _Pragma("unroll")                                                 \
    for (int ks_ = 0; ks_ < 2; ++ks_) {                               \
      const int kb_ = ks_ * 64 + kc4 * 16;                            \
      bf16x8 b1_[3], b2_[3], b3_[3];                                  \
      _Pragma("unroll")                                               \
      for (int nt_ = 0; nt_ < 3; ++nt_) {                             \
        int br_ = nt_ * 16 + l15;                                     \
        int bo_ = br_ * 128 + (kb_ ^ ((br_ & 7) << 4));               \
        b1_[nt_] = *(const bf16x8*)((const char*)&Bs[buf][0][0] + bo_); \
        b2_[nt_] = *(const bf16x8*)((const char*)&Bs[buf][1][0] + bo_); \
        b3_[nt_] = *(const bf16x8*)((const char*)&Bs[buf][2][0] + bo_); \
      }                                                               \
      _Pragma("unroll")                                               \
      for (int nt_ = 0; nt_ < 3; ++nt_) {                             \
        acc[nt_] = __builtin_amdgcn_mfma_f32_16x16x32_bf16(AR[ks_][2], b1_[nt_], acc[nt_], 0, 0, 0); \
        acc[nt_] = __builtin_amdgcn_mfma_f32_16x16x32_bf16(AR[ks_][0], b3_[nt_], acc[nt_], 0, 0, 0); \
        acc[nt_] = __builtin_amdgcn_mfma_f32_16x16x32_bf16(AR[ks_][1], b2_[nt_], acc[nt_], 0, 0, 0); \
        acc[nt_] = __builtin_amdgcn_mfma_f32_16x16x32_bf16(AR[ks_][1], b1_[nt_], acc[nt_], 0, 0, 0); \
        acc[nt_] = __builtin_amdgcn_mfma_f32_16x16x32_bf16(AR[ks_][0], b2_[nt_], acc[nt_], 0, 0, 0); \
        acc[nt_] = __builtin_amdgcn_mfma_f32_16x16x32_bf16(AR[ks_][0], b1_[nt_], acc[nt_], 0, 0, 0); \
      }                                                               \
    }                                                                 \
  } while (0)

  f32x4 acc[3];
#pragma unroll
  for (int nt = 0; nt < 3; ++nt) acc[nt] = (f32x4){0.f, 0.f, 0.f, 0.f};

  bf16x8 aA[2][3], aB[2][3];
  LOAD_A(aA, 0); STAGE_B(0, 0);
  LOAD_A(aB, 1); STAGE_B(1, 1);

#pragma unroll
  for (int kt2 = 0; kt2 < 8; ++kt2) {
    const int kte = kt2 * 2, kto = kte + 1;
    asm volatile("s_waitcnt vmcnt(15)" ::: "memory");
    __builtin_amdgcn_s_barrier();
    __builtin_amdgcn_sched_barrier(0);
    COMPUTE_G(aA, 0);
    __builtin_amdgcn_sched_barrier(0);
    __builtin_amdgcn_s_barrier();
    if (kte + 2 < 16) { LOAD_A(aA, kte + 2); STAGE_B(0, kte + 2); }
    if (kto < 15) {
      asm volatile("s_waitcnt vmcnt(15)" ::: "memory");
    } else {
      asm volatile("s_waitcnt vmcnt(0)" ::: "memory");
    }
    __builtin_amdgcn_s_barrier();
    __builtin_amdgcn_sched_barrier(0);
    COMPUTE_G(aB, 1);
    __builtin_amdgcn_sched_barrier(0);
    __builtin_amdgcn_s_barrier();
    if (kto + 2 < 16) { LOAD_A(aB, kto + 2); STAGE_B(1, kto + 2); }
  }
#undef STAGE_B
#undef LOAD_A
#undef COMPUTE_G

  // ---- in-register gate math ----
  const bool low = (l15 < 8);
  const int j = b * 8 + l15;
  float bi_r = 0.f, bi_z = 0.f, bi_n = 0.f, bh_r = 0.f, bh_z = 0.f, bh_n = 0.f;
  if (low) {
    bi_r = b_ih[j]; bi_z = b_ih[HD + j]; bi_n = b_ih[2 * HD + j];
    bh_r = b_hh[j]; bh_z = b_hh[HD + j]; bh_n = b_hh[2 * HD + j];
  }
#pragma unroll
  for (int r = 0; r < 4; ++r) {
    float v0 = acc[0][r], v1 = acc[1][r], v2 = acc[2][r];
    float p0 = __shfl_xor(v0, 8);    // iz
    float p1 = __shfl_xor(v1, 8);    // hr
    float p2 = __shfl_xor(v2, 8);    // hn
    if (low) {
      float gir = (t == 0) ? bi_r : (v0 + bi_r);
      float giz = (t == 0) ? bi_z : (p0 + bi_z);
      float gin = (t == 0) ? bi_n : (v1 + bi_n);
      float ghr = p1 + bh_r;
      float ghz = v2 + bh_z;
      float ghn = p2 + bh_n;
      float rr = 1.0f / (1.0f + expf(-(gir + ghr)));
      float zz = 1.0f / (1.0f + expf(-(giz + ghz)));
      float nn = tanhf(gin + rr * ghn);
      int i = hb * 32 + w * 16 + (lane >> 4) * 4 + r;
      int idx = i * HD + j;
      float hp = h[idx];
      float hn2 = (1.0f - zz) * nn + zz * hp;
      h[idx] = hn2;
      size_t o = ((size_t)t * BBATCH + i) * HD + j;
      outs[o] = hn2;
      ushort a = f2bf_rne(hn2);
      outs_bf[o] = a;
      float r1 = hn2 - bf2f(a);
      ushort bb2 = f2bf_rne(r1);
      float r2 = r1 - bf2f(bb2);
      h1[idx] = a; h2[idx] = bb2; h3[idx] = f2bf_rne(r2);
    }
  }
}

// ---------------- bf16 MFMA fc_out prefilter v5 ----------------------------
// grid (16 rb, 250 cb), XCD-pinned A. BK=64 (R4's proven fragment geometry),
// double-buffered with counted vmcnt(8); epilogue LDS overlaid on staging.
__global__ __launch_bounds__(256) void gemm_out_mfma(
    const ushort* __restrict__ Abf, const ushort* __restrict__ Bbf,
    const float* __restrict__ b_out, u64* __restrict__ keys) {
  __shared__ ushort Sm[2][2][8192];   // [buf][A/B][128*64] = 64 KB
  float* Cs = (float*)&Sm[0][0][0];                   // 17 KB overlay
  u64* pkL1 = (u64*)((char*)&Sm[0][0][0] + 17024);    // 8 KB
  u64* pkL2 = pkL1 + 1024;                            // 2 KB

  const int tid = threadIdx.x;
  const int lane = tid & 63;
  const int wid = tid >> 6;
  const int wr = wid >> 1, wc = wid & 1;
  const int cb = blockIdx.y;
  const int n0 = cb * 128;
  const int r0 = blockIdx.x * 128;

  const ushort* Ag = Abf + (size_t)r0 * HD;
  const ushort* Bg = Bbf + (size_t)n0 * HD;
  const int rc = lane >> 3;
  const int gr8 = ((lane & 7) ^ rc) * 8;
  const int l15 = lane & 15;
  const int kseg = (lane >> 4) * 16;     // byte offset of lane's 8-bf16 seg

#define STAGE_OUT(buf, kt) do {                                      \
    ushort* SA_ = &Sm[buf][0][0];                                    \
    ushort* SB_ = &Sm[buf][1][0];                                    \
    const int k0_ = (kt) * 64;                                       \
    _Pragma("unroll")                                                \
    for (int c_ = 0; c_ < 4; ++c_) {                                 \
      int ch_ = wid * 4 + c_;                                        \
      int row_ = ch_ * 8 + rc;                                       \
      gload16(Ag + (size_t)row_ * HD + k0_ + gr8, SA_ + ch_ * 512);  \
      gload16(Bg + (size_t)row_ * HD + k0_ + gr8, SB_ + ch_ * 512);  \
    }                                                                \
  } while (0)

#define COMPUTE_OUT(buf) do {                                        \
    const ushort* SA_ = &Sm[buf][0][0];                              \
    const ushort* SB_ = &Sm[buf][1][0];                              \
    _Pragma("unroll")                                                \
    for (int ks_ = 0; ks_ < 2; ++ks_) {                              \
      bf16x8 a_[4], b_[4];                                           \
      const int kb_ = ks_ * 64 + kseg;                               \
      _Pragma("unroll")                                              \
      for (int m_ = 0; m_ < 4; ++m_) {                               \
        int row_ = wr * 64 + m_ * 16 + l15;                          \
        int off_ = row_ * 128 + (kb_ ^ ((row_ & 7) << 4));           \
        a_[m_] = *(const bf16x8*)((const char*)SA_ + off_);          \
      }                                                              \
      _Pragma("unroll")                                              \
      for (int n_ = 0; n_ < 4; ++n_) {                               \
        int row_ = wc * 64 + n_ * 16 + l15;                          \
        int off_ = row_ * 128 + (kb_ ^ ((row_ & 7) << 4));           \
        b_[n_] = *(const bf16x8*)((const char*)SB_ + off_);          \
      }                                                              \
      _Pragma("unroll")                                              \
      for (int m_ = 0; m_ < 4; ++m_)                                 \
        _Pragma("unroll")                                            \
        for (int n_ = 0; n_ < 4; ++n_)                               \
          acc[m_][n_] = __builtin_amdgcn_mfma_f32_16x16x32_bf16(     \
              a_[m_], b_[n_], acc[m_][n_], 0, 0, 0);                 \
    }                                                                \
  } while (0)

  float bo[4];
#pragma unroll
  for (int n = 0; n < 4; ++n) bo[n] = b_out[n0 + wc * 64 + n * 16 + l15];

  f32x4 acc[4][4];
#pragma unroll
  for (int m = 0; m < 4; ++m)
#pragma unroll
    for (int n = 0; n < 4; ++n) acc[m][n] = (f32x4){0.f, 0.f, 0.f, 0.f};

  STAGE_OUT(0, 0);
  int p = 0;
  for (int kt = 0; kt < 16; ++kt) {
    if (kt < 15) {
      STAGE_OUT(p ^ 1, kt + 1);
      asm volatile("s_waitcnt vmcnt(8)" ::: "memory");  // buf p done; p^1 flying
    } else {
      asm volatile("s_waitcnt vmcnt(0)" ::: "memory");
    }
    __builtin_amdgcn_s_barrier();
    __builtin_amdgcn_sched_barrier(0);
    COMPUTE_OUT(p);
    __builtin_amdgcn_sched_barrier(0);
    __builtin_amdgcn_s_barrier();
    p ^= 1;
  }
  __syncthreads();   // staging LDS dead; epilogue overlays it

  // epilogue: fully unrolled q; parallel 3-level top-4 per row over 128 cols
#pragma unroll
  for (int q = 0; q < 4; ++q) {
    if (wr == (q >> 1)) {
#pragma unroll
      for (int mi = 0; mi < 2; ++mi) {
        const int m = (q & 1) * 2 + mi;
#pragma unroll
        for (int n = 0; n < 4; ++n) {
          int c = wc * 64 + n * 16 + l15;
#pragma unroll
          for (int j = 0; j < 4; ++j) {
            int lr = mi * 16 + (lane >> 4) * 4 + j;
            Cs[lr * 133 + c] = acc[m][n][j] + bo[n];
          }
        }
      }
    }
    __syncthreads();
    {  // level 1: 256 threads, 16 cols each
      int rr = tid >> 3, seg = tid & 7;
      const float* rp = Cs + rr * 133 + seg * 16;
      u64 t4[4] = {0, 0, 0, 0};
#pragma unroll
      for (int c = 0; c < 16; ++c) insert4(t4, packkey(rp[c], n0 + seg * 16 + c));
      u64* d = pkL1 + (rr * 8 + seg) * 4;
      d[0] = t4[0]; d[1] = t4[1]; d[2] = t4[2]; d[3] = t4[3];
    }
    __syncthreads();
    if (tid < 64) {  // level 2: merge 4 sets of 4
      int rr = tid >> 1, hf = tid & 1;
      const u64* s = pkL1 + (rr * 8 + hf * 4) * 4;
      u64 t4[4] = {s[0], s[1], s[2], s[3]};
#pragma unroll
      for (int e = 4; e < 16; ++e) insert4(t4, s[e]);
      u64* d = pkL2 + tid * 4;
      d[0] = t4[0]; d[1] = t4[1]; d[2] = t4[2]; d[3] = t4[3];
    }
    __syncthreads();
    if (tid < 32) {  // level 3: merge 2 sets, write out
      const u64* s = pkL2 + tid * 8;
      u64 t4[4] = {s[0], s[1], s[2], s[3]};
      insert4(t4, s[4]); insert4(t4, s[5]); insert4(t4, s[6]); insert4(t4, s[7]);
      int grow = r0 + q * 32 + tid;
      u64* kp2 = keys + ((size_t)grow * NCB + cb) * 4;
      kp2[0] = t4[0]; kp2[1] = t4[1]; kp2[2] = t4[2]; kp2[3] = t4[3];
    }
    __syncthreads();
  }
#undef STAGE_OUT
#undef COMPUTE_OUT
}

// ---------------- per-row merge v2: 1 wave, reg-resident, no barriers ------
__global__ __launch_bounds__(64) void merge_sample2(
    const u64* __restrict__ keys, const float* __restrict__ outs,
    const float* __restrict__ W_out, const float* __restrict__ b_out,
    int* __restrict__ out) {
  const int r = blockIdx.x;
  const int lane = threadIdx.x;
  __shared__ float row_f[1024];
  {
    const float4* src = (const float4*)(outs + (size_t)r * HD);
    float4* dst = (float4*)row_f;
#pragma unroll
    for (int m = 0; m < 4; ++m) dst[lane + m * 64] = src[lane + m * 64];
  }
  u64 t8[8] = {0, 0, 0, 0, 0, 0, 0, 0};
  const u64* KR = keys + (size_t)r * 1000;
#pragma unroll
  for (int m = 0; m < 16; ++m) {
    int i = lane + (m << 6);
    if (i < 1000) {
      u64 k = KR[i];
      if (k > t8[7]) {
        t8[7] = k;
#pragma unroll
        for (int e = 7; e > 0; --e) {
          u64 hi = t8[e - 1], lo = t8[e];
          t8[e - 1] = (lo > hi) ? lo : hi;
          t8[e]     = (lo > hi) ? hi : lo;
        }
      }
    }
  }
  const int mycand = lane >> 2;
  u64 myw = 0;
#pragma unroll
  for (int it = 0; it < NCAND; ++it) {
    u64 bmax = t8[0];
#pragma unroll
    for (int o = 32; o; o >>= 1) {
      u64 x = __shfl_xor(bmax, o);
      if (x > bmax) bmax = x;
    }
    if (it == mycand) myw = bmax;
    if (t8[0] == bmax) {
#pragma unroll
      for (int e = 0; e < 7; ++e) t8[e] = t8[e + 1];
      t8[7] = 0;
    }
  }
  const int myvi = (int)(~(u32)(myw & 0xffffffffu));
  float mysum;
  {
    const float4* wrow = (const float4*)(W_out + (size_t)myvi * HD);
    const float4* rf = (const float4*)row_f;
    const int q = lane & 3;
    float s = 0.f;
#pragma unroll
    for (int m2 = 0; m2 < 64; ++m2) {
      float4 a = rf[q + m2 * 4];
      float4 bb = wrow[q + m2 * 4];
      s += a.x * bb.x; s += a.y * bb.y; s += a.z * bb.z; s += a.w * bb.w;
    }
    s += __shfl_xor(s, 1);
    s += __shfl_xor(s, 2);
    mysum = s + b_out[myvi];
  }
  float v[NCAND]; int vi[NCAND];
#pragma unroll
  for (int c = 0; c < NCAND; ++c) {
    v[c] = __shfl(mysum, c * 4);
    vi[c] = __shfl(myvi, c * 4);
  }
  if (lane == 0) {
#pragma unroll
    for (int a = 0; a < 8; ++a)
#pragma unroll
      for (int b2 = a + 1; b2 < NCAND; ++b2) {
        bool sw = (v[b2] > v[a]) || (v[b2] == v[a] && vi[b2] < vi[a]);
        if (sw) {
          float tf = v[a]; v[a] = v[b2]; v[b2] = tf;
          int ti = vi[a]; vi[a] = vi[b2]; vi[b2] = ti;
        }
      }
    const float M = v[0];
    const float TINY = 1.17549435e-38f;
    float best = -3.4e38f; int bi = 0;
#pragma unroll
    for (int k = 0; k < 8; ++k) {
      float lp = v[k] - M;
      u32 bits = jax_random_bits((u32)(r * 8 + k));
      float f = __uint_as_float((bits >> 9) | 0x3f800000u) - 1.0f;
      float u = f * (1.0f - TINY) + TINY;
      u = fmaxf(TINY, u);
      float g = -logf(-logf(u));
      float s = g + lp;
      if (s > best) { best = s; bi = k; }
    }
    int t = r >> 6, b = r & 63;
    out[b * TSTEP + t] = vi[bi];
  }
}

extern "C" void kernel_launch(void* const* d_in, const int* in_sizes, int n_in,
                              void* d_out, int out_size, void* d_ws, size_t ws_size,
                              hipStream_t stream) {
  (void)in_sizes; (void)n_in; (void)out_size; (void)ws_size;
  const float* vectors = (const float*)d_in[0];
  const float* W_fc_in = (const float*)d_in[1];
  const float* b_fc_in = (const float*)d_in[2];
  const float* W_ih    = (const float*)d_in[3];
  const float* W_hh    = (const float*)d_in[4];
  const float* b_ih    = (const float*)d_in[5];
  const float* b_hh    = (const float*)d_in[6];
  const float* W_out   = (const float*)d_in[7];
  const float* b_out   = (const float*)d_in[8];
  int* out = (int*)d_out;

  char* w = (char*)d_ws;
  float* h = (float*)w;          w += (size_t)BBATCH * HD * 4;        // 256 KB
  float* outs = (float*)w;       w += (size_t)NROWS * HD * 4;         // 8 MB
  ushort* outs_bf = (ushort*)w;  w += (size_t)NROWS * HD * 2;         // 4 MB
  ushort* Wbf = (ushort*)w;      w += (size_t)VOCAB * HD * 2;         // 65.5 MB
  // X region: permuted Wg splits live through the GRU; keys aliases after.
  char* X = w;                   w += (size_t)3 * GATE6 * HD * 2;     // 37.75 MB
  ushort* Wg1 = (ushort*)X;
  ushort* Wg2 = Wg1 + (size_t)GATE6 * HD;
  ushort* Wg3 = Wg2 + (size_t)GATE6 * HD;
  u64* keys = (u64*)X;                                               // alias
  ushort* h1 = (ushort*)w;       w += (size_t)BBATCH * HD * 2;        // 128 KB
  ushort* h2 = (ushort*)w;       w += (size_t)BBATCH * HD * 2;        // 128 KB
  ushort* h3 = (ushort*)w;       w += (size_t)BBATCH * HD * 2;        // 128 KB
  float* part = (float*)w;       // fc_in partials: 4*64*1024 fp32 = 1 MB

  // one-time weight conversions
  tobf16<<<4096, 256, 0, stream>>>(W_out, Wbf, VOCAB * HD / 8);
  tobf16x3_gruP<<<GATE6 * (HD / 8) / 256, 256, 0, stream>>>(W_ih, W_hh,
                                                            Wg1, Wg2, Wg3);

  // fc_in: h0 = vectors @ W_fc_in^T + b_fc_in  (fp32, split-K=4)
  gemm64_nt<<<dim3(32, 4), 256, 0, stream>>>(vectors, W_fc_in, part);
  combine_fcin<<<256, 256, 0, stream>>>(part, b_fc_in, h, h1, h2, h3);

  // 32 GRU steps: hb-pairs co-located per XCD (W' L2 sharing)
  for (int t = 0; t < TSTEP; ++t)
    gru_step<<<256, 128, 0, stream>>>(Wg1, Wg2, Wg3, b_ih, b_hh,
                                      h, outs, outs_bf, h1, h2, h3, t);

  // bf16 MFMA prefilter over the vocab (BK=64 counted-vmcnt pipeline)
  gemm_out_mfma<<<dim3(16, NCB), 256, 0, stream>>>(outs_bf, Wbf, b_out, keys);

  // per-row top-16 select + exact fp32 rescore + Threefry/Gumbel sampling
  merge_sample2<<<NROWS, 64, 0, stream>>>(keys, outs, W_out, b_out, out);
}